// Round 2
// baseline (1384.196 us; speedup 1.0000x reference)
//
#include <hip/hip_runtime.h>
#include <hip/hip_bf16.h>

// Problem constants (fixed instance):
//   B=128 graphs, N=1024 nodes/graph, F=128 in-feats, D=256 hidden, E=8192 edges/graph
//   n_total = 131072 nodes, out = 131072 x 256 fp32
#define NNODES   1024
#define NGRAPH   128
#define NTOTAL   (NNODES * NGRAPH)   // 131072
#define FEAT_IN  128
#define DHID     256
#define ECAP     (16384 + NNODES)    // CSR capacity (edges + self loops), generous

// ---------------- build: degree, dinv, CSR (by dst, incl self-loops), zero stats ----------------
__global__ __launch_bounds__(1024) void build_kernel(
    const int* __restrict__ ei, int E,
    int* __restrict__ offs, int* __restrict__ ecol, float* __restrict__ ew,
    float* __restrict__ stats /* 1024 floats zeroed (stats1+stats2) */)
{
    __shared__ int scnt[NNODES];
    __shared__ int bufA[NNODES];
    __shared__ int bufB[NNODES];
    __shared__ float sdinv[NNODES];
    const int t = threadIdx.x;

    scnt[t] = 1;              // self-loop
    stats[t] = 0.0f;
    __syncthreads();

    for (int e = t; e < E; e += 1024)
        atomicAdd(&scnt[ei[E + e]], 1);   // dst = ei[1][e]
    __syncthreads();

    const int deg = scnt[t];
    const float di = rsqrtf((float)deg);
    sdinv[t] = di;
    bufA[t] = deg;
    __syncthreads();

    // inclusive scan over degrees (Hillis-Steele, double buffer)
    int* src = bufA; int* dst = bufB;
    for (int d = 1; d < NNODES; d <<= 1) {
        dst[t] = src[t] + (t >= d ? src[t - d] : 0);
        __syncthreads();
        int* tmp = src; src = dst; dst = tmp;
    }
    const int excl = src[t] - deg;  // exclusive prefix
    offs[t] = excl;
    if (t == NNODES - 1) offs[NNODES] = src[t];

    // self loop placed first; cursor continues after it
    ecol[excl] = t;
    ew[excl] = di * di;
    scnt[t] = excl + 1;  // reuse as cursor
    __syncthreads();

    for (int e = t; e < E; e += 1024) {
        const int s = ei[e];       // src = ei[0][e]
        const int d = ei[E + e];   // dst = ei[1][e]
        const int pos = atomicAdd(&scnt[d], 1);
        ecol[pos] = s;
        ew[pos] = sdinv[s] * sdinv[d];
    }
}

// ---------------- GEMM: C[M][N] = BN(A)[M][K] @ W[K][N]  (fp32 vector, 128x128 tile, 8x8 micro) ----
#define BM 128
#define BN 128
#define BK 16
#define PAD 132   // padded LDS row stride (floats); 132*4=528B, 16B-aligned rows

template<bool BNIN>
__global__ __launch_bounds__(256) void gemm_kernel(
    const float* __restrict__ A, const float* __restrict__ W,
    float* __restrict__ C, int K,
    const float* __restrict__ scale, const float* __restrict__ shift)
{
    __shared__ float As[BK][PAD];
    __shared__ float Ws[BK][PAD];
    const int N = DHID;
    const int m0 = blockIdx.y * BM;
    const int n0 = blockIdx.x * BN;
    const int t = threadIdx.x;

    const int rm = (t >> 4) * 8;   // 0..120
    const int cn = (t & 15) * 8;

    float acc[8][8] = {};

    for (int k0 = 0; k0 < K; k0 += BK) {
        // load A tile: 128 rows x 16 k, 512 float4, 2 per thread
        #pragma unroll
        for (int h = 0; h < 2; ++h) {
            const int q = t + h * 256;
            const int row = q >> 2, kq = q & 3;
            const float4 v = *(const float4*)(A + (size_t)(m0 + row) * K + k0 + kq * 4);
            float vv[4] = {v.x, v.y, v.z, v.w};
            #pragma unroll
            for (int j = 0; j < 4; ++j) {
                const int kk = kq * 4 + j;
                float x = vv[j];
                if (BNIN) x = x * scale[k0 + kk] + shift[k0 + kk];
                As[kk][row] = x;
            }
        }
        // load W tile: 16 k x 128 n
        #pragma unroll
        for (int h = 0; h < 2; ++h) {
            const int q = t + h * 256;
            const int k = q >> 5, nq = q & 31;
            const float4 v = *(const float4*)(W + (size_t)(k0 + k) * N + n0 + nq * 4);
            *(float4*)&Ws[k][nq * 4] = v;
        }
        __syncthreads();

        #pragma unroll
        for (int k = 0; k < BK; ++k) {
            const float4 a0 = *(const float4*)&As[k][rm];
            const float4 a1 = *(const float4*)&As[k][rm + 4];
            const float4 b0 = *(const float4*)&Ws[k][cn];
            const float4 b1 = *(const float4*)&Ws[k][cn + 4];
            const float a[8] = {a0.x,a0.y,a0.z,a0.w,a1.x,a1.y,a1.z,a1.w};
            const float b[8] = {b0.x,b0.y,b0.z,b0.w,b1.x,b1.y,b1.z,b1.w};
            #pragma unroll
            for (int i = 0; i < 8; ++i)
                #pragma unroll
                for (int j = 0; j < 8; ++j)
                    acc[i][j] += a[i] * b[j];
        }
        __syncthreads();
    }

    #pragma unroll
    for (int i = 0; i < 8; ++i) {
        float4* p = (float4*)(C + (size_t)(m0 + rm + i) * N + n0 + cn);
        p[0] = make_float4(acc[i][0], acc[i][1], acc[i][2], acc[i][3]);
        p[1] = make_float4(acc[i][4], acc[i][5], acc[i][6], acc[i][7]);
    }
}

// ---------------- SpMM: agg = Anorm @ hw (per graph), + bias, ReLU, optional stats partials -------
#define NB 16   // dst nodes per block

template<bool STATS>
__global__ __launch_bounds__(256) void spmm_kernel(
    const float* __restrict__ hw, const float* __restrict__ bias,
    float* __restrict__ hout, float* __restrict__ partials,
    const int* __restrict__ offs, const int* __restrict__ ecol,
    const float* __restrict__ ew)
{
    const int b = blockIdx.x;                 // 8192 blocks
    const int g = b >> 6;                     // graph (1024/NB = 64 blocks/graph)
    const int nb = (b & 63) * NB;             // local node base
    const int t = threadIdx.x;                // feature 0..255
    const float* __restrict__ hwg = hw + (size_t)g * NNODES * DHID;
    const float bv = bias[t];

    float bsum = 0.0f, bsq = 0.0f;
    #pragma unroll 1
    for (int i = 0; i < NB; ++i) {
        const int ln = nb + i;
        const int e0 = offs[ln], e1 = offs[ln + 1];
        float acc = 0.0f;
        for (int e = e0; e < e1; ++e) {
            const int c = ecol[e];
            const float w = ew[e];
            acc += w * hwg[(size_t)c * DHID + t];
        }
        float val = acc + bv;
        val = fmaxf(val, 0.0f);
        hout[((size_t)g * NNODES + ln) * DHID + t] = val;
        if (STATS) { bsum += val; bsq += val * val; }
    }
    if (STATS) {
        partials[(size_t)b * 512 + t] = bsum;
        partials[(size_t)b * 512 + 256 + t] = bsq;
    }
}

// ---------------- stats reduce + BN scale/shift finalize -----------------------------------------
__global__ __launch_bounds__(256) void reduce_kernel(
    const float* __restrict__ partials, float* __restrict__ stats, int P)
{
    const int t = threadIdx.x;
    const int per = P / gridDim.x;
    const int p0 = blockIdx.x * per;
    float s = 0.0f, q = 0.0f;
    for (int p = p0; p < p0 + per; ++p) {
        s += partials[(size_t)p * 512 + t];
        q += partials[(size_t)p * 512 + 256 + t];
    }
    atomicAdd(&stats[t], s);
    atomicAdd(&stats[256 + t], q);
}

__global__ __launch_bounds__(256) void finalize_kernel(
    const float* __restrict__ stats, const float* __restrict__ gamma,
    const float* __restrict__ beta, float* __restrict__ scale,
    float* __restrict__ shift)
{
    const int t = threadIdx.x;
    const float n = (float)NTOTAL;
    const float mean = stats[t] / n;
    const float var = stats[256 + t] / n - mean * mean;
    const float sc = gamma[t] * rsqrtf(var + 1e-5f);
    scale[t] = sc;
    shift[t] = beta[t] - mean * sc;
}

// ---------------- launch -------------------------------------------------------------------------
extern "C" void kernel_launch(void* const* d_in, const int* in_sizes, int n_in,
                              void* d_out, int out_size, void* d_ws, size_t ws_size,
                              hipStream_t stream)
{
    const float* x      = (const float*)d_in[0];
    const int*   ei     = (const int*)d_in[1];
    const float* W1     = (const float*)d_in[3];
    const float* b1     = (const float*)d_in[4];
    const float* W2     = (const float*)d_in[5];
    const float* b2     = (const float*)d_in[6];
    const float* W3     = (const float*)d_in[7];
    const float* b3     = (const float*)d_in[8];
    const float* gamma1 = (const float*)d_in[9];
    const float* beta1  = (const float*)d_in[10];
    const float* gamma2 = (const float*)d_in[11];
    const float* beta2  = (const float*)d_in[12];
    float* out = (float*)d_out;

    const int E = in_sizes[1] / 2;   // 8192

    // workspace layout
    char* w = (char*)d_ws;
    float* hw       = (float*)w;                                  // 131072*256*4 = 134217728
    float* partials = (float*)(w + 134217728);                    // 8192*512*4   = 16777216
    char* meta = w + 134217728 + 16777216;
    int*   offs   = (int*)meta;             meta += 1056 * 4;
    int*   ecol   = (int*)meta;             meta += ECAP * 4;
    float* ew     = (float*)meta;           meta += ECAP * 4;
    float* stats1 = (float*)meta;           meta += 512 * 4;      // stats1+stats2 contiguous
    float* stats2 = (float*)meta;           meta += 512 * 4;
    float* scale1 = (float*)meta;           meta += 256 * 4;
    float* shift1 = (float*)meta;           meta += 256 * 4;
    float* scale2 = (float*)meta;           meta += 256 * 4;
    float* shift2 = (float*)meta;           meta += 256 * 4;

    const dim3 ggrid(DHID / BN, NTOTAL / BM);   // (2, 1024)
    const int  P = NTOTAL / NB;                 // 8192

    build_kernel<<<1, 1024, 0, stream>>>(ei, E, offs, ecol, ew, stats1);

    // Layer 1: hw = x @ W1 ; h1 = relu(A@hw + b1) -> d_out ; stats1
    gemm_kernel<false><<<ggrid, 256, 0, stream>>>(x, W1, hw, FEAT_IN, nullptr, nullptr);
    spmm_kernel<true><<<P, 256, 0, stream>>>(hw, b1, out, partials, offs, ecol, ew);
    reduce_kernel<<<64, 256, 0, stream>>>(partials, stats1, P);
    finalize_kernel<<<1, 256, 0, stream>>>(stats1, gamma1, beta1, scale1, shift1);

    // Layer 2: hw = BN(h1) @ W2 ; h2 = relu(A@hw + b2) -> d_out ; stats2
    gemm_kernel<true><<<ggrid, 256, 0, stream>>>(out, W2, hw, DHID, scale1, shift1);
    spmm_kernel<true><<<P, 256, 0, stream>>>(hw, b2, out, partials, offs, ecol, ew);
    reduce_kernel<<<64, 256, 0, stream>>>(partials, stats2, P);
    finalize_kernel<<<1, 256, 0, stream>>>(stats2, gamma2, beta2, scale2, shift2);

    // Layer 3: hw = BN(h2) @ W3 ; out = relu(A@hw + b3)
    gemm_kernel<true><<<ggrid, 256, 0, stream>>>(out, W3, hw, DHID, scale2, shift2);
    spmm_kernel<false><<<P, 256, 0, stream>>>(hw, b3, out, nullptr, offs, ecol, ew);
}

// Round 3
// 1296.975 us; speedup vs baseline: 1.0672x; 1.0672x over previous
//
#include <hip/hip_runtime.h>
#include <hip/hip_bf16.h>

// Problem constants (fixed instance):
//   B=128 graphs, N=1024 nodes/graph, F=128 in-feats, D=256 hidden, E=8192 edges/graph
//   n_total = 131072 nodes, out = 131072 x 256 fp32
#define NNODES   1024
#define NGRAPH   128
#define NTOTAL   (NNODES * NGRAPH)   // 131072
#define FEAT_IN  128
#define DHID     256
#define ECAP     (16384 + NNODES)    // CSR capacity (edges + self loops), generous

// ---------------- build: degree, dinv, CSR (by dst, incl self-loops), zero stats ----------------
__global__ __launch_bounds__(1024) void build_kernel(
    const int* __restrict__ ei, int E,
    int* __restrict__ offs, int* __restrict__ ecol, float* __restrict__ ew,
    float* __restrict__ stats /* 1024 floats zeroed (stats1+stats2) */)
{
    __shared__ int scnt[NNODES];
    __shared__ int bufA[NNODES];
    __shared__ int bufB[NNODES];
    __shared__ float sdinv[NNODES];
    const int t = threadIdx.x;

    scnt[t] = 1;              // self-loop
    stats[t] = 0.0f;
    __syncthreads();

    for (int e = t; e < E; e += 1024)
        atomicAdd(&scnt[ei[E + e]], 1);   // dst = ei[1][e]
    __syncthreads();

    const int deg = scnt[t];
    const float di = rsqrtf((float)deg);
    sdinv[t] = di;
    bufA[t] = deg;
    __syncthreads();

    // inclusive scan over degrees (Hillis-Steele, double buffer)
    int* src = bufA; int* dst = bufB;
    for (int d = 1; d < NNODES; d <<= 1) {
        dst[t] = src[t] + (t >= d ? src[t - d] : 0);
        __syncthreads();
        int* tmp = src; src = dst; dst = tmp;
    }
    const int excl = src[t] - deg;  // exclusive prefix
    offs[t] = excl;
    if (t == NNODES - 1) offs[NNODES] = src[t];

    // self loop placed first; cursor continues after it
    ecol[excl] = t;
    ew[excl] = di * di;
    scnt[t] = excl + 1;  // reuse as cursor
    __syncthreads();

    for (int e = t; e < E; e += 1024) {
        const int s = ei[e];       // src = ei[0][e]
        const int d = ei[E + e];   // dst = ei[1][e]
        const int pos = atomicAdd(&scnt[d], 1);
        ecol[pos] = s;
        ew[pos] = sdinv[s] * sdinv[d];
    }
}

// ---------------- GEMM: C[M][N] = BN(A)[M][K] @ W[K][N]  (fp32 vector, 128x128 tile, 8x8 micro) ----
#define BM 128
#define BN 128
#define BK 16
#define PAD 132   // padded LDS row stride (floats); 132*4=528B, 16B-aligned rows

template<bool BNIN>
__global__ __launch_bounds__(256) void gemm_kernel(
    const float* __restrict__ A, const float* __restrict__ W,
    float* __restrict__ C, int K,
    const float* __restrict__ scale, const float* __restrict__ shift)
{
    __shared__ float As[BK][PAD];
    __shared__ float Ws[BK][PAD];
    const int N = DHID;
    const int m0 = blockIdx.y * BM;
    const int n0 = blockIdx.x * BN;
    const int t = threadIdx.x;

    const int rm = (t >> 4) * 8;   // 0..120
    const int cn = (t & 15) * 8;

    float acc[8][8] = {};

    for (int k0 = 0; k0 < K; k0 += BK) {
        // load A tile: 128 rows x 16 k, 512 float4, 2 per thread
        #pragma unroll
        for (int h = 0; h < 2; ++h) {
            const int q = t + h * 256;
            const int row = q >> 2, kq = q & 3;
            const float4 v = *(const float4*)(A + (size_t)(m0 + row) * K + k0 + kq * 4);
            float vv[4] = {v.x, v.y, v.z, v.w};
            #pragma unroll
            for (int j = 0; j < 4; ++j) {
                const int kk = kq * 4 + j;
                float x = vv[j];
                if (BNIN) x = x * scale[k0 + kk] + shift[k0 + kk];
                As[kk][row] = x;
            }
        }
        // load W tile: 16 k x 128 n
        #pragma unroll
        for (int h = 0; h < 2; ++h) {
            const int q = t + h * 256;
            const int k = q >> 5, nq = q & 31;
            const float4 v = *(const float4*)(W + (size_t)(k0 + k) * N + n0 + nq * 4);
            *(float4*)&Ws[k][nq * 4] = v;
        }
        __syncthreads();

        #pragma unroll
        for (int k = 0; k < BK; ++k) {
            const float4 a0 = *(const float4*)&As[k][rm];
            const float4 a1 = *(const float4*)&As[k][rm + 4];
            const float4 b0 = *(const float4*)&Ws[k][cn];
            const float4 b1 = *(const float4*)&Ws[k][cn + 4];
            const float a[8] = {a0.x,a0.y,a0.z,a0.w,a1.x,a1.y,a1.z,a1.w};
            const float b[8] = {b0.x,b0.y,b0.z,b0.w,b1.x,b1.y,b1.z,b1.w};
            #pragma unroll
            for (int i = 0; i < 8; ++i)
                #pragma unroll
                for (int j = 0; j < 8; ++j)
                    acc[i][j] += a[i] * b[j];
        }
        __syncthreads();
    }

    #pragma unroll
    for (int i = 0; i < 8; ++i) {
        float4* p = (float4*)(C + (size_t)(m0 + rm + i) * N + n0 + cn);
        p[0] = make_float4(acc[i][0], acc[i][1], acc[i][2], acc[i][3]);
        p[1] = make_float4(acc[i][4], acc[i][5], acc[i][6], acc[i][7]);
    }
}

// ---------------- SpMM: agg = Anorm @ hw (per graph), + bias, ReLU, optional stats partials -------
// XCD-aware mapping: all 64 blocks of a graph land on the same XCD (assuming
// round-robin workgroup->XCD dispatch, b%8). 16 graphs per XCD, slab = 1 MB
// each, L2 = 4 MB/XCD -> each slab fetched from HBM once.
// 4 concurrent node accumulators per thread -> 4 independent load chains.
#define NB 16   // dst nodes per block

template<bool STATS>
__global__ __launch_bounds__(256) void spmm_kernel(
    const float* __restrict__ hw, const float* __restrict__ bias,
    float* __restrict__ hout, float* __restrict__ partials,
    const int* __restrict__ offs, const int* __restrict__ ecol,
    const float* __restrict__ ew)
{
    const int b = blockIdx.x;                 // 8192 blocks
    const int xcd = b & 7;
    const int idx = b >> 3;                   // 0..1023
    const int g  = (idx >> 6) * 8 + xcd;      // graph: all 64 blocks of g share XCD
    const int nb = (idx & 63) * NB;           // local node base
    const int t = threadIdx.x;                // feature 0..255
    const float* __restrict__ hwg = hw + (size_t)g * NNODES * DHID;
    const float bv = bias[t];

    float bsum = 0.0f, bsq = 0.0f;
    #pragma unroll 1
    for (int i0 = 0; i0 < NB; i0 += 4) {
        int e0[4], cnt[4];
        int emax = 0;
        #pragma unroll
        for (int i = 0; i < 4; ++i) {
            const int ln = nb + i0 + i;
            e0[i] = offs[ln];
            cnt[i] = offs[ln + 1] - e0[i];
            emax = max(emax, cnt[i]);
        }
        float acc[4] = {0.0f, 0.0f, 0.0f, 0.0f};
        #pragma unroll 1
        for (int k = 0; k < emax; ++k) {
            #pragma unroll
            for (int i = 0; i < 4; ++i) {
                if (k < cnt[i]) {   // wave-uniform predicate
                    const int e = e0[i] + k;
                    acc[i] += ew[e] * hwg[(size_t)ecol[e] * DHID + t];
                }
            }
        }
        #pragma unroll
        for (int i = 0; i < 4; ++i) {
            float val = fmaxf(acc[i] + bv, 0.0f);
            hout[((size_t)g * NNODES + nb + i0 + i) * DHID + t] = val;
            if (STATS) { bsum += val; bsq += val * val; }
        }
    }
    if (STATS) {
        partials[(size_t)b * 512 + t] = bsum;
        partials[(size_t)b * 512 + 256 + t] = bsq;
    }
}

// ---------------- stats reduce + BN scale/shift finalize -----------------------------------------
__global__ __launch_bounds__(256) void reduce_kernel(
    const float* __restrict__ partials, float* __restrict__ stats, int P)
{
    const int t = threadIdx.x;
    const int per = P / gridDim.x;
    const int p0 = blockIdx.x * per;
    float s = 0.0f, q = 0.0f;
    for (int p = p0; p < p0 + per; ++p) {
        s += partials[(size_t)p * 512 + t];
        q += partials[(size_t)p * 512 + 256 + t];
    }
    atomicAdd(&stats[t], s);
    atomicAdd(&stats[256 + t], q);
}

__global__ __launch_bounds__(256) void finalize_kernel(
    const float* __restrict__ stats, const float* __restrict__ gamma,
    const float* __restrict__ beta, float* __restrict__ scale,
    float* __restrict__ shift)
{
    const int t = threadIdx.x;
    const float n = (float)NTOTAL;
    const float mean = stats[t] / n;
    const float var = stats[256 + t] / n - mean * mean;
    const float sc = gamma[t] * rsqrtf(var + 1e-5f);
    scale[t] = sc;
    shift[t] = beta[t] - mean * sc;
}

// ---------------- launch -------------------------------------------------------------------------
extern "C" void kernel_launch(void* const* d_in, const int* in_sizes, int n_in,
                              void* d_out, int out_size, void* d_ws, size_t ws_size,
                              hipStream_t stream)
{
    const float* x      = (const float*)d_in[0];
    const int*   ei     = (const int*)d_in[1];
    const float* W1     = (const float*)d_in[3];
    const float* b1     = (const float*)d_in[4];
    const float* W2     = (const float*)d_in[5];
    const float* b2     = (const float*)d_in[6];
    const float* W3     = (const float*)d_in[7];
    const float* b3     = (const float*)d_in[8];
    const float* gamma1 = (const float*)d_in[9];
    const float* beta1  = (const float*)d_in[10];
    const float* gamma2 = (const float*)d_in[11];
    const float* beta2  = (const float*)d_in[12];
    float* out = (float*)d_out;

    const int E = in_sizes[1] / 2;   // 8192

    // workspace layout
    char* w = (char*)d_ws;
    float* hw       = (float*)w;                                  // 131072*256*4 = 134217728
    float* partials = (float*)(w + 134217728);                    // 8192*512*4   = 16777216
    char* meta = w + 134217728 + 16777216;
    int*   offs   = (int*)meta;             meta += 1056 * 4;
    int*   ecol   = (int*)meta;             meta += ECAP * 4;
    float* ew     = (float*)meta;           meta += ECAP * 4;
    float* stats1 = (float*)meta;           meta += 512 * 4;      // stats1+stats2 contiguous
    float* stats2 = (float*)meta;           meta += 512 * 4;
    float* scale1 = (float*)meta;           meta += 256 * 4;
    float* shift1 = (float*)meta;           meta += 256 * 4;
    float* scale2 = (float*)meta;           meta += 256 * 4;
    float* shift2 = (float*)meta;           meta += 256 * 4;

    const dim3 ggrid(DHID / BN, NTOTAL / BM);   // (2, 1024)
    const int  P = NTOTAL / NB;                 // 8192

    build_kernel<<<1, 1024, 0, stream>>>(ei, E, offs, ecol, ew, stats1);

    // Layer 1: hw = x @ W1 ; h1 = relu(A@hw + b1) -> d_out ; stats1
    gemm_kernel<false><<<ggrid, 256, 0, stream>>>(x, W1, hw, FEAT_IN, nullptr, nullptr);
    spmm_kernel<true><<<P, 256, 0, stream>>>(hw, b1, out, partials, offs, ecol, ew);
    reduce_kernel<<<64, 256, 0, stream>>>(partials, stats1, P);
    finalize_kernel<<<1, 256, 0, stream>>>(stats1, gamma1, beta1, scale1, shift1);

    // Layer 2: hw = BN(h1) @ W2 ; h2 = relu(A@hw + b2) -> d_out ; stats2
    gemm_kernel<true><<<ggrid, 256, 0, stream>>>(out, W2, hw, DHID, scale1, shift1);
    spmm_kernel<true><<<P, 256, 0, stream>>>(hw, b2, out, partials, offs, ecol, ew);
    reduce_kernel<<<64, 256, 0, stream>>>(partials, stats2, P);
    finalize_kernel<<<1, 256, 0, stream>>>(stats2, gamma2, beta2, scale2, shift2);

    // Layer 3: hw = BN(h2) @ W3 ; out = relu(A@hw + b3)
    gemm_kernel<true><<<ggrid, 256, 0, stream>>>(out, W3, hw, DHID, scale2, shift2);
    spmm_kernel<false><<<P, 256, 0, stream>>>(hw, b3, out, nullptr, offs, ecol, ew);
}

// Round 4
// 541.238 us; speedup vs baseline: 2.5575x; 2.3963x over previous
//
#include <hip/hip_runtime.h>

// Problem constants (fixed instance):
//   B=128 graphs, N=1024 nodes/graph, F=128 in-feats, D=256 hidden, E=8192 edges/graph
#define NNODES   1024
#define NGRAPH   128
#define NTOTAL   (NNODES * NGRAPH)   // 131072
#define FEAT_IN  128
#define DHID     256
#define ECAP     (16384 + NNODES)    // CSR capacity

typedef __attribute__((ext_vector_type(8))) short bf16x8;
typedef __attribute__((ext_vector_type(4))) float f32x4;
typedef __attribute__((ext_vector_type(8))) unsigned short us8;

__device__ __forceinline__ unsigned short f2bf(float f) {
    unsigned int u = __float_as_uint(f);
    u += 0x7fffu + ((u >> 16) & 1u);           // RNE
    return (unsigned short)(u >> 16);
}
__device__ __forceinline__ float bf2f(unsigned short s) {
    return __uint_as_float(((unsigned int)s) << 16);
}

// ---------------- build: degree, dinv, CSR (by dst, incl self-loops), zero stats ----------------
__global__ __launch_bounds__(1024) void build_kernel(
    const int* __restrict__ ei, int E,
    int* __restrict__ offs, int* __restrict__ ecol, float* __restrict__ ew,
    float* __restrict__ stats /* 1024 floats zeroed */)
{
    __shared__ int scnt[NNODES];
    __shared__ int bufA[NNODES];
    __shared__ int bufB[NNODES];
    __shared__ float sdinv[NNODES];
    const int t = threadIdx.x;

    scnt[t] = 1;              // self-loop
    stats[t] = 0.0f;
    __syncthreads();

    for (int e = t; e < E; e += 1024)
        atomicAdd(&scnt[ei[E + e]], 1);   // dst = ei[1][e]
    __syncthreads();

    const int deg = scnt[t];
    const float di = rsqrtf((float)deg);
    sdinv[t] = di;
    bufA[t] = deg;
    __syncthreads();

    int* src = bufA; int* dst = bufB;
    for (int d = 1; d < NNODES; d <<= 1) {
        dst[t] = src[t] + (t >= d ? src[t - d] : 0);
        __syncthreads();
        int* tmp = src; src = dst; dst = tmp;
    }
    const int excl = src[t] - deg;
    offs[t] = excl;
    if (t == NNODES - 1) offs[NNODES] = src[t];

    ecol[excl] = t;
    ew[excl] = di * di;
    scnt[t] = excl + 1;
    __syncthreads();

    for (int e = t; e < E; e += 1024) {
        const int s = ei[e];
        const int d = ei[E + e];
        const int pos = atomicAdd(&scnt[d], 1);
        ecol[pos] = s;
        ew[pos] = sdinv[s] * sdinv[d];
    }
}

// ---------------- prep: x fp32 -> bf16 ; W [K][256] fp32 -> Wt [256][K] bf16 ---------------------
__global__ __launch_bounds__(256) void xcvt_kernel(const float* __restrict__ x,
                                                   unsigned short* __restrict__ xb, int n)
{
    for (int i = (blockIdx.x * 256 + threadIdx.x) * 4; i < n; i += gridDim.x * 256 * 4) {
        const float4 v = *(const float4*)(x + i);
        ushort4 o;
        o.x = f2bf(v.x); o.y = f2bf(v.y); o.z = f2bf(v.z); o.w = f2bf(v.w);
        *(ushort4*)(xb + i) = o;
    }
}

__global__ __launch_bounds__(256) void wt_kernel(const float* __restrict__ W,
                                                 unsigned short* __restrict__ Wt, int K)
{
    const int k = blockIdx.x, n = threadIdx.x;   // grid = K, block = 256
    Wt[(size_t)n * K + k] = f2bf(W[(size_t)k * 256 + n]);
}

// ---------------- MFMA GEMM: C[M][256] = bf16( BN(A) @ W ) ---------------------------------------
// A [M][K] bf16, Wt [256][K] bf16. 128x128 block tile, 4 waves (2x2), 4x4 frags of 16x16x32.
// LDS tiles stored [row][ASTR] with k contiguous -> ds_read_b128 frags, conflict-free (stride 80B).
#define ASTR 40

template<bool BNIN>
__global__ __launch_bounds__(256) void mgemm_kernel(
    const unsigned short* __restrict__ A,
    const unsigned short* __restrict__ Wt,
    unsigned short* __restrict__ C, int K,
    const float* __restrict__ scale, const float* __restrict__ shift)
{
    __shared__ unsigned short sA[128 * ASTR];
    __shared__ unsigned short sB[128 * ASTR];
    __shared__ float sSc[DHID];
    __shared__ float sSh[DHID];

    const int t = threadIdx.x;
    const int m0 = blockIdx.y * 128;
    const int n0 = blockIdx.x * 128;
    const int w = t >> 6, lane = t & 63;
    const int wr = w >> 1, wc = w & 1;
    const int lr = lane & 15, lk = lane >> 4;
    const int srow = t >> 1, skh = (t & 1) * 16;

    if (BNIN) { sSc[t] = scale[t]; sSh[t] = shift[t]; }

    f32x4 acc[4][4];
    #pragma unroll
    for (int i = 0; i < 4; ++i)
        #pragma unroll
        for (int j = 0; j < 4; ++j)
            acc[i][j] = (f32x4){0.f, 0.f, 0.f, 0.f};

    __syncthreads();   // sSc/sSh visible before first staging

    for (int k0 = 0; k0 < K; k0 += 32) {
        // stage A: row = srow, k-range [k0+skh, +16)
        const unsigned short* ga = A + (size_t)(m0 + srow) * K + k0 + skh;
        us8 a0 = *(const us8*)ga;
        us8 a1 = *(const us8*)(ga + 8);
        if (BNIN) {
            #pragma unroll
            for (int j = 0; j < 8; ++j) {
                const int kk = k0 + skh + j;
                a0[j] = f2bf(bf2f(a0[j]) * sSc[kk] + sSh[kk]);
                a1[j] = f2bf(bf2f(a1[j]) * sSc[kk + 8] + sSh[kk + 8]);
            }
        }
        *(us8*)&sA[srow * ASTR + skh] = a0;
        *(us8*)&sA[srow * ASTR + skh + 8] = a1;
        // stage B: col = srow (row n0+srow of Wt), same k-range
        const unsigned short* gb = Wt + (size_t)(n0 + srow) * K + k0 + skh;
        *(us8*)&sB[srow * ASTR + skh] = *(const us8*)gb;
        *(us8*)&sB[srow * ASTR + skh + 8] = *(const us8*)(gb + 8);
        __syncthreads();

        bf16x8 af[4], bfr[4];
        #pragma unroll
        for (int f = 0; f < 4; ++f) {
            af[f]  = *(const bf16x8*)&sA[(wr * 64 + f * 16 + lr) * ASTR + lk * 8];
            bfr[f] = *(const bf16x8*)&sB[(wc * 64 + f * 16 + lr) * ASTR + lk * 8];
        }
        #pragma unroll
        for (int mf = 0; mf < 4; ++mf)
            #pragma unroll
            for (int nf = 0; nf < 4; ++nf)
                acc[mf][nf] = __builtin_amdgcn_mfma_f32_16x16x32_bf16(
                    af[mf], bfr[nf], acc[mf][nf], 0, 0, 0);
        __syncthreads();
    }

    // C/D layout: col = lane&15, row = (lane>>4)*4 + reg
    #pragma unroll
    for (int mf = 0; mf < 4; ++mf) {
        const int rbase = m0 + wr * 64 + mf * 16 + lk * 4;
        #pragma unroll
        for (int nf = 0; nf < 4; ++nf) {
            const int c = n0 + wc * 64 + nf * 16 + lr;
            #pragma unroll
            for (int r = 0; r < 4; ++r)
                C[(size_t)(rbase + r) * DHID + c] = f2bf(acc[mf][nf][r]);
        }
    }
}

// ---------------- SpMM: h = relu(Anorm @ hw + b), bf16 in, bf16/fp32 out, stats partials ---------
// Edge metadata preloaded to LDS (kills the dependent index-load chain),
// 8-deep independent gather unroll, XCD-affine graph mapping for L2 residency.
#define NB 16
#define ECAPB 512

template<bool STATS, bool OUTF32>
__global__ __launch_bounds__(256) void spmm_kernel(
    const unsigned short* __restrict__ hw, const float* __restrict__ bias,
    void* __restrict__ hout, float* __restrict__ partials,
    const int* __restrict__ offs, const int* __restrict__ ecol,
    const float* __restrict__ ew)
{
    __shared__ int se[ECAPB];
    __shared__ float swt[ECAPB];
    __shared__ int soff[NB + 1];

    const int b = blockIdx.x;                 // 8192 blocks
    const int xcd = b & 7;
    const int idx = b >> 3;
    const int g  = (idx >> 6) * 8 + xcd;      // all 64 blocks of graph g on one XCD
    const int nb = (idx & 63) * NB;
    const int t = threadIdx.x;
    const unsigned short* __restrict__ hwg = hw + (size_t)g * NNODES * DHID;

    if (t <= NB) soff[t] = offs[nb + t];
    __syncthreads();
    const int base = soff[0];
    const int tot = soff[NB] - base;          // ~150, cap 512
    for (int e = t; e < tot; e += 256) { se[e] = ecol[base + e]; swt[e] = ew[base + e]; }
    __syncthreads();

    const float bv = bias[t];
    float bsum = 0.0f, bsq = 0.0f;
    #pragma unroll 1
    for (int i = 0; i < NB; ++i) {
        const int s = soff[i] - base, e = soff[i + 1] - base;
        float a0=0,a1=0,a2=0,a3=0,a4=0,a5=0,a6=0,a7=0;
        int k = s;
        #pragma unroll 1
        for (; k + 8 <= e; k += 8) {
            a0 += swt[k+0] * bf2f(hwg[(size_t)se[k+0] * DHID + t]);
            a1 += swt[k+1] * bf2f(hwg[(size_t)se[k+1] * DHID + t]);
            a2 += swt[k+2] * bf2f(hwg[(size_t)se[k+2] * DHID + t]);
            a3 += swt[k+3] * bf2f(hwg[(size_t)se[k+3] * DHID + t]);
            a4 += swt[k+4] * bf2f(hwg[(size_t)se[k+4] * DHID + t]);
            a5 += swt[k+5] * bf2f(hwg[(size_t)se[k+5] * DHID + t]);
            a6 += swt[k+6] * bf2f(hwg[(size_t)se[k+6] * DHID + t]);
            a7 += swt[k+7] * bf2f(hwg[(size_t)se[k+7] * DHID + t]);
        }
        if (k     < e) a0 += swt[k  ] * bf2f(hwg[(size_t)se[k  ] * DHID + t]);
        if (k + 1 < e) a1 += swt[k+1] * bf2f(hwg[(size_t)se[k+1] * DHID + t]);
        if (k + 2 < e) a2 += swt[k+2] * bf2f(hwg[(size_t)se[k+2] * DHID + t]);
        if (k + 3 < e) a3 += swt[k+3] * bf2f(hwg[(size_t)se[k+3] * DHID + t]);
        if (k + 4 < e) a4 += swt[k+4] * bf2f(hwg[(size_t)se[k+4] * DHID + t]);
        if (k + 5 < e) a5 += swt[k+5] * bf2f(hwg[(size_t)se[k+5] * DHID + t]);
        if (k + 6 < e) a6 += swt[k+6] * bf2f(hwg[(size_t)se[k+6] * DHID + t]);

        float val = fmaxf(((a0 + a1) + (a2 + a3)) + ((a4 + a5) + (a6 + a7)) + bv, 0.0f);
        const size_t oi = ((size_t)g * NNODES + nb + i) * DHID + t;
        if (OUTF32) ((float*)hout)[oi] = val;
        else        ((unsigned short*)hout)[oi] = f2bf(val);
        if (STATS) { bsum += val; bsq += val * val; }
    }
    if (STATS) {
        partials[(size_t)b * 512 + t] = bsum;
        partials[(size_t)b * 512 + 256 + t] = bsq;
    }
}

// ---------------- stats reduce + BN scale/shift finalize -----------------------------------------
__global__ __launch_bounds__(256) void reduce_kernel(
    const float* __restrict__ partials, float* __restrict__ stats, int P)
{
    const int t = threadIdx.x;
    const int per = P / gridDim.x;
    const int p0 = blockIdx.x * per;
    float s = 0.0f, q = 0.0f;
    for (int p = p0; p < p0 + per; ++p) {
        s += partials[(size_t)p * 512 + t];
        q += partials[(size_t)p * 512 + 256 + t];
    }
    atomicAdd(&stats[t], s);
    atomicAdd(&stats[256 + t], q);
}

__global__ __launch_bounds__(256) void finalize_kernel(
    const float* __restrict__ stats, const float* __restrict__ gamma,
    const float* __restrict__ beta, float* __restrict__ scale,
    float* __restrict__ shift)
{
    const int t = threadIdx.x;
    const float n = (float)NTOTAL;
    const float mean = stats[t] / n;
    const float var = stats[256 + t] / n - mean * mean;
    const float sc = gamma[t] * rsqrtf(var + 1e-5f);
    scale[t] = sc;
    shift[t] = beta[t] - mean * sc;
}

// ---------------- launch -------------------------------------------------------------------------
extern "C" void kernel_launch(void* const* d_in, const int* in_sizes, int n_in,
                              void* d_out, int out_size, void* d_ws, size_t ws_size,
                              hipStream_t stream)
{
    const float* x      = (const float*)d_in[0];
    const int*   ei     = (const int*)d_in[1];
    const float* W1     = (const float*)d_in[3];
    const float* b1     = (const float*)d_in[4];
    const float* W2     = (const float*)d_in[5];
    const float* b2     = (const float*)d_in[6];
    const float* W3     = (const float*)d_in[7];
    const float* b3     = (const float*)d_in[8];
    const float* gamma1 = (const float*)d_in[9];
    const float* beta1  = (const float*)d_in[10];
    const float* gamma2 = (const float*)d_in[11];
    const float* beta2  = (const float*)d_in[12];
    float* out = (float*)d_out;

    const int E = in_sizes[1] / 2;   // 8192

    // workspace layout (total ~151.5 MB)
    char* w = (char*)d_ws;
    unsigned short* hA = (unsigned short*)w;                 // x_bf16 (33.5MB) then h bf16 (67MB) — sequential reuse
    unsigned short* hw = (unsigned short*)(w + 67108864);    // 67 MB
    float* partials    = (float*)(w + 134217728);            // 16.8 MB
    char* meta = w + 150994944;
    int*   offs   = (int*)meta;            meta += 4352;
    int*   ecol   = (int*)meta;            meta += ECAP * 4;
    float* ewt    = (float*)meta;          meta += ECAP * 4;
    float* stats1 = (float*)meta;          meta += 512 * 4;   // stats1+stats2 contiguous (1024 f zeroed by build)
    float* stats2 = (float*)meta;          meta += 512 * 4;
    float* scale1 = (float*)meta;          meta += 256 * 4;
    float* shift1 = (float*)meta;          meta += 256 * 4;
    float* scale2 = (float*)meta;          meta += 256 * 4;
    float* shift2 = (float*)meta;          meta += 256 * 4;
    unsigned short* wt1 = (unsigned short*)meta;  meta += 256 * 128 * 2;
    unsigned short* wt2 = (unsigned short*)meta;  meta += 256 * 256 * 2;
    unsigned short* wt3 = (unsigned short*)meta;  meta += 256 * 256 * 2;

    const dim3 ggrid(2, NTOTAL / 128);   // (n-tiles, m-tiles) = (2, 1024)
    const int  P = NTOTAL / NB;          // 8192

    build_kernel<<<1, 1024, 0, stream>>>(ei, E, offs, ecol, ewt, stats1);
    xcvt_kernel<<<1024, 256, 0, stream>>>(x, hA, NTOTAL * FEAT_IN);
    wt_kernel<<<FEAT_IN, 256, 0, stream>>>(W1, wt1, FEAT_IN);
    wt_kernel<<<DHID, 256, 0, stream>>>(W2, wt2, DHID);
    wt_kernel<<<DHID, 256, 0, stream>>>(W3, wt3, DHID);

    // Layer 1
    mgemm_kernel<false><<<ggrid, 256, 0, stream>>>(hA, wt1, hw, FEAT_IN, nullptr, nullptr);
    spmm_kernel<true, false><<<P, 256, 0, stream>>>(hw, b1, hA, partials, offs, ecol, ewt);
    reduce_kernel<<<64, 256, 0, stream>>>(partials, stats1, P);
    finalize_kernel<<<1, 256, 0, stream>>>(stats1, gamma1, beta1, scale1, shift1);

    // Layer 2
    mgemm_kernel<true><<<ggrid, 256, 0, stream>>>(hA, wt2, hw, DHID, scale1, shift1);
    spmm_kernel<true, false><<<P, 256, 0, stream>>>(hw, b2, hA, partials, offs, ecol, ewt);
    reduce_kernel<<<64, 256, 0, stream>>>(partials, stats2, P);
    finalize_kernel<<<1, 256, 0, stream>>>(stats2, gamma2, beta2, scale2, shift2);

    // Layer 3 (fp32 output, no stats)
    mgemm_kernel<true><<<ggrid, 256, 0, stream>>>(hA, wt3, hw, DHID, scale2, shift2);
    spmm_kernel<false, true><<<P, 256, 0, stream>>>(hw, b3, out, nullptr, offs, ecol, ewt);
}

// Round 5
// 382.276 us; speedup vs baseline: 3.6209x; 1.4158x over previous
//
#include <hip/hip_runtime.h>

// Problem constants (fixed instance):
//   B=128 graphs, N=1024 nodes/graph, F=128 in-feats, D=256 hidden, E=8192 edges/graph
#define NNODES   1024
#define NGRAPH   128
#define NTOTAL   (NNODES * NGRAPH)   // 131072
#define FEAT_IN  128
#define DHID     256
#define ECAP     (16384 + NNODES)    // CSR capacity

typedef __attribute__((ext_vector_type(8))) short bf16x8;
typedef __attribute__((ext_vector_type(4))) float f32x4;
typedef __attribute__((ext_vector_type(8))) unsigned short us8;
typedef __attribute__((ext_vector_type(4))) unsigned short us4;

__device__ __forceinline__ unsigned short f2bf(float f) {
    unsigned int u = __float_as_uint(f);
    u += 0x7fffu + ((u >> 16) & 1u);           // RNE
    return (unsigned short)(u >> 16);
}
__device__ __forceinline__ float bf2f(unsigned short s) {
    return __uint_as_float(((unsigned int)s) << 16);
}
__device__ __forceinline__ float blo(unsigned int u) { return __uint_as_float(u << 16); }
__device__ __forceinline__ float bhi(unsigned int u) { return __uint_as_float(u & 0xffff0000u); }

// ---------------- build: degree, dinv, CSR (by dst, incl self-loops), zero stats ----------------
__global__ __launch_bounds__(1024) void build_kernel(
    const int* __restrict__ ei, int E,
    int* __restrict__ offs, int* __restrict__ ecol, float* __restrict__ ew,
    float* __restrict__ stats /* 1024 floats zeroed */)
{
    __shared__ int scnt[NNODES];
    __shared__ int bufA[NNODES];
    __shared__ int bufB[NNODES];
    __shared__ float sdinv[NNODES];
    const int t = threadIdx.x;

    scnt[t] = 1;              // self-loop
    stats[t] = 0.0f;
    __syncthreads();

    for (int e = t; e < E; e += 1024)
        atomicAdd(&scnt[ei[E + e]], 1);   // dst = ei[1][e]
    __syncthreads();

    const int deg = scnt[t];
    const float di = rsqrtf((float)deg);
    sdinv[t] = di;
    bufA[t] = deg;
    __syncthreads();

    int* src = bufA; int* dst = bufB;
    for (int d = 1; d < NNODES; d <<= 1) {
        dst[t] = src[t] + (t >= d ? src[t - d] : 0);
        __syncthreads();
        int* tmp = src; src = dst; dst = tmp;
    }
    const int excl = src[t] - deg;
    offs[t] = excl;
    if (t == NNODES - 1) offs[NNODES] = src[t];

    ecol[excl] = t;
    ew[excl] = di * di;
    scnt[t] = excl + 1;
    __syncthreads();

    for (int e = t; e < E; e += 1024) {
        const int s = ei[e];
        const int d = ei[E + e];
        const int pos = atomicAdd(&scnt[d], 1);
        ecol[pos] = s;
        ew[pos] = sdinv[s] * sdinv[d];
    }
}

// ---------------- prep: x fp32 -> bf16 ; W [K][256] fp32 -> Wt [256][K] bf16 ---------------------
__global__ __launch_bounds__(256) void xcvt_kernel(const float* __restrict__ x,
                                                   unsigned short* __restrict__ xb, int n)
{
    for (int i = (blockIdx.x * 256 + threadIdx.x) * 4; i < n; i += gridDim.x * 256 * 4) {
        const float4 v = *(const float4*)(x + i);
        ushort4 o;
        o.x = f2bf(v.x); o.y = f2bf(v.y); o.z = f2bf(v.z); o.w = f2bf(v.w);
        *(ushort4*)(xb + i) = o;
    }
}

__global__ __launch_bounds__(256) void wt_kernel(const float* __restrict__ W,
                                                 unsigned short* __restrict__ Wt, int K)
{
    const int k = blockIdx.x, n = threadIdx.x;   // grid = K, block = 256
    Wt[(size_t)n * K + k] = f2bf(W[(size_t)k * 256 + n]);
}

// ---------------- MFMA GEMM: C[M][256] = bf16( BN(A) @ W ) ---------------------------------------
// A [M][K] bf16, Wt [256][K] bf16. 128x128 block tile, 4 waves (2x2), 4x4 frags of 16x16x32.
// LDS tiles stored [row][ASTR] with k contiguous -> ds_read_b128 frags, conflict-free (stride 80B).
#define ASTR 40

template<bool BNIN>
__global__ __launch_bounds__(256) void mgemm_kernel(
    const unsigned short* __restrict__ A,
    const unsigned short* __restrict__ Wt,
    unsigned short* __restrict__ C, int K,
    const float* __restrict__ scale, const float* __restrict__ shift)
{
    __shared__ unsigned short sA[128 * ASTR];
    __shared__ unsigned short sB[128 * ASTR];
    __shared__ float sSc[DHID];
    __shared__ float sSh[DHID];

    const int t = threadIdx.x;
    const int m0 = blockIdx.y * 128;
    const int n0 = blockIdx.x * 128;
    const int w = t >> 6, lane = t & 63;
    const int wr = w >> 1, wc = w & 1;
    const int lr = lane & 15, lk = lane >> 4;
    const int srow = t >> 1, skh = (t & 1) * 16;

    if (BNIN) { sSc[t] = scale[t]; sSh[t] = shift[t]; }

    f32x4 acc[4][4];
    #pragma unroll
    for (int i = 0; i < 4; ++i)
        #pragma unroll
        for (int j = 0; j < 4; ++j)
            acc[i][j] = (f32x4){0.f, 0.f, 0.f, 0.f};

    __syncthreads();   // sSc/sSh visible before first staging

    for (int k0 = 0; k0 < K; k0 += 32) {
        // stage A: row = srow, k-range [k0+skh, +16)
        const unsigned short* ga = A + (size_t)(m0 + srow) * K + k0 + skh;
        us8 a0 = *(const us8*)ga;
        us8 a1 = *(const us8*)(ga + 8);
        if (BNIN) {
            #pragma unroll
            for (int j = 0; j < 8; ++j) {
                const int kk = k0 + skh + j;
                a0[j] = f2bf(bf2f(a0[j]) * sSc[kk] + sSh[kk]);
                a1[j] = f2bf(bf2f(a1[j]) * sSc[kk + 8] + sSh[kk + 8]);
            }
        }
        *(us8*)&sA[srow * ASTR + skh] = a0;
        *(us8*)&sA[srow * ASTR + skh + 8] = a1;
        // stage B: col = srow (row n0+srow of Wt), same k-range
        const unsigned short* gb = Wt + (size_t)(n0 + srow) * K + k0 + skh;
        *(us8*)&sB[srow * ASTR + skh] = *(const us8*)gb;
        *(us8*)&sB[srow * ASTR + skh + 8] = *(const us8*)(gb + 8);
        __syncthreads();

        bf16x8 af[4], bfr[4];
        #pragma unroll
        for (int f = 0; f < 4; ++f) {
            af[f]  = *(const bf16x8*)&sA[(wr * 64 + f * 16 + lr) * ASTR + lk * 8];
            bfr[f] = *(const bf16x8*)&sB[(wc * 64 + f * 16 + lr) * ASTR + lk * 8];
        }
        #pragma unroll
        for (int mf = 0; mf < 4; ++mf)
            #pragma unroll
            for (int nf = 0; nf < 4; ++nf)
                acc[mf][nf] = __builtin_amdgcn_mfma_f32_16x16x32_bf16(
                    af[mf], bfr[nf], acc[mf][nf], 0, 0, 0);
        __syncthreads();
    }

    // C/D layout: col = lane&15, row = (lane>>4)*4 + reg
    #pragma unroll
    for (int mf = 0; mf < 4; ++mf) {
        const int rbase = m0 + wr * 64 + mf * 16 + lk * 4;
        #pragma unroll
        for (int nf = 0; nf < 4; ++nf) {
            const int c = n0 + wc * 64 + nf * 16 + lr;
            #pragma unroll
            for (int r = 0; r < 4; ++r)
                C[(size_t)(rbase + r) * DHID + c] = f2bf(acc[mf][nf][r]);
        }
    }
}

// ---------------- SpMM: h = relu(Anorm @ hw + b), vectorized 4-feat/lane -------------------------
// Lane l owns features 4l..4l+3 (8B uint2 loads); wave w owns 4 of the block's 16 nodes.
// Edge metadata preloaded to LDS; 4-deep edge unroll -> 4 loads in flight;
// XCD-affine graph mapping keeps each graph's hw slab in one L2.
#define NB 16
#define ECAPB 512

template<bool STATS, bool OUTF32>
__global__ __launch_bounds__(256) void spmm_kernel(
    const unsigned short* __restrict__ hw, const float* __restrict__ bias,
    void* __restrict__ hout, float* __restrict__ partials,
    const int* __restrict__ offs, const int* __restrict__ ecol,
    const float* __restrict__ ew)
{
    __shared__ int se[ECAPB];
    __shared__ float swt[ECAPB];
    __shared__ int soff[NB + 1];
    __shared__ float spartS[4][256];
    __shared__ float spartQ[4][256];

    const int b = blockIdx.x;                 // 8192 blocks
    const int xcd = b & 7;
    const int idx = b >> 3;
    const int g  = (idx >> 6) * 8 + xcd;      // all 64 blocks of graph g on one XCD
    const int nb = (idx & 63) * NB;
    const int t = threadIdx.x;
    const int w = t >> 6, l = t & 63;
    const int f0 = l * 4;
    const unsigned short* __restrict__ hwg = hw + (size_t)g * NNODES * DHID;

    if (t <= NB) soff[t] = offs[nb + t];
    __syncthreads();
    const int base = soff[0];
    const int tot = soff[NB] - base;          // ~150, cap 512
    for (int e = t; e < tot; e += 256) { se[e] = ecol[base + e]; swt[e] = ew[base + e]; }
    __syncthreads();

    const float4 bv = *(const float4*)(bias + f0);
    float ps0=0, ps1=0, ps2=0, ps3=0, pq0=0, pq1=0, pq2=0, pq3=0;

    #pragma unroll 1
    for (int j = 0; j < 4; ++j) {
        const int i = w * 4 + j;
        const int s = soff[i] - base, e = soff[i + 1] - base;
        float a0=0, a1=0, a2=0, a3=0;
        int k = s;
        #pragma unroll 1
        for (; k + 4 <= e; k += 4) {
            const uint2 u0 = *(const uint2*)(hwg + (size_t)se[k+0] * DHID + f0);
            const uint2 u1 = *(const uint2*)(hwg + (size_t)se[k+1] * DHID + f0);
            const uint2 u2 = *(const uint2*)(hwg + (size_t)se[k+2] * DHID + f0);
            const uint2 u3 = *(const uint2*)(hwg + (size_t)se[k+3] * DHID + f0);
            const float w0 = swt[k+0], w1 = swt[k+1], w2 = swt[k+2], w3 = swt[k+3];
            a0 = fmaf(w0, blo(u0.x), a0); a1 = fmaf(w0, bhi(u0.x), a1);
            a2 = fmaf(w0, blo(u0.y), a2); a3 = fmaf(w0, bhi(u0.y), a3);
            a0 = fmaf(w1, blo(u1.x), a0); a1 = fmaf(w1, bhi(u1.x), a1);
            a2 = fmaf(w1, blo(u1.y), a2); a3 = fmaf(w1, bhi(u1.y), a3);
            a0 = fmaf(w2, blo(u2.x), a0); a1 = fmaf(w2, bhi(u2.x), a1);
            a2 = fmaf(w2, blo(u2.y), a2); a3 = fmaf(w2, bhi(u2.y), a3);
            a0 = fmaf(w3, blo(u3.x), a0); a1 = fmaf(w3, bhi(u3.x), a1);
            a2 = fmaf(w3, blo(u3.y), a2); a3 = fmaf(w3, bhi(u3.y), a3);
        }
        #pragma unroll 1
        for (; k < e; ++k) {
            const uint2 u = *(const uint2*)(hwg + (size_t)se[k] * DHID + f0);
            const float wk = swt[k];
            a0 = fmaf(wk, blo(u.x), a0); a1 = fmaf(wk, bhi(u.x), a1);
            a2 = fmaf(wk, blo(u.y), a2); a3 = fmaf(wk, bhi(u.y), a3);
        }

        const float v0 = fmaxf(a0 + bv.x, 0.0f);
        const float v1 = fmaxf(a1 + bv.y, 0.0f);
        const float v2 = fmaxf(a2 + bv.z, 0.0f);
        const float v3 = fmaxf(a3 + bv.w, 0.0f);
        const size_t orow = (size_t)g * NNODES + nb + i;
        if (OUTF32) {
            *(float4*)((float*)hout + orow * DHID + f0) = make_float4(v0, v1, v2, v3);
        } else {
            us4 o; o[0] = f2bf(v0); o[1] = f2bf(v1); o[2] = f2bf(v2); o[3] = f2bf(v3);
            *(us4*)((unsigned short*)hout + orow * DHID + f0) = o;
        }
        if (STATS) {
            ps0 += v0; ps1 += v1; ps2 += v2; ps3 += v3;
            pq0 += v0*v0; pq1 += v1*v1; pq2 += v2*v2; pq3 += v3*v3;
        }
    }

    if (STATS) {
        spartS[w][f0+0] = ps0; spartS[w][f0+1] = ps1; spartS[w][f0+2] = ps2; spartS[w][f0+3] = ps3;
        spartQ[w][f0+0] = pq0; spartQ[w][f0+1] = pq1; spartQ[w][f0+2] = pq2; spartQ[w][f0+3] = pq3;
        __syncthreads();
        const float ss = spartS[0][t] + spartS[1][t] + spartS[2][t] + spartS[3][t];
        const float sq = spartQ[0][t] + spartQ[1][t] + spartQ[2][t] + spartQ[3][t];
        partials[(size_t)b * 512 + t] = ss;
        partials[(size_t)b * 512 + 256 + t] = sq;
    }
}

// ---------------- stats reduce + BN scale/shift finalize -----------------------------------------
__global__ __launch_bounds__(256) void reduce_kernel(
    const float* __restrict__ partials, float* __restrict__ stats, int P)
{
    const int t = threadIdx.x;
    const int per = P / gridDim.x;
    const int p0 = blockIdx.x * per;
    float s = 0.0f, q = 0.0f;
    for (int p = p0; p < p0 + per; ++p) {
        s += partials[(size_t)p * 512 + t];
        q += partials[(size_t)p * 512 + 256 + t];
    }
    atomicAdd(&stats[t], s);
    atomicAdd(&stats[256 + t], q);
}

__global__ __launch_bounds__(256) void finalize_kernel(
    const float* __restrict__ stats, const float* __restrict__ gamma,
    const float* __restrict__ beta, float* __restrict__ scale,
    float* __restrict__ shift)
{
    const int t = threadIdx.x;
    const float n = (float)NTOTAL;
    const float mean = stats[t] / n;
    const float var = stats[256 + t] / n - mean * mean;
    const float sc = gamma[t] * rsqrtf(var + 1e-5f);
    scale[t] = sc;
    shift[t] = beta[t] - mean * sc;
}

// ---------------- launch -------------------------------------------------------------------------
extern "C" void kernel_launch(void* const* d_in, const int* in_sizes, int n_in,
                              void* d_out, int out_size, void* d_ws, size_t ws_size,
                              hipStream_t stream)
{
    const float* x      = (const float*)d_in[0];
    const int*   ei     = (const int*)d_in[1];
    const float* W1     = (const float*)d_in[3];
    const float* b1     = (const float*)d_in[4];
    const float* W2     = (const float*)d_in[5];
    const float* b2     = (const float*)d_in[6];
    const float* W3     = (const float*)d_in[7];
    const float* b3     = (const float*)d_in[8];
    const float* gamma1 = (const float*)d_in[9];
    const float* beta1  = (const float*)d_in[10];
    const float* gamma2 = (const float*)d_in[11];
    const float* beta2  = (const float*)d_in[12];
    float* out = (float*)d_out;

    const int E = in_sizes[1] / 2;   // 8192

    // workspace layout (total ~151.5 MB)
    char* w = (char*)d_ws;
    unsigned short* hA = (unsigned short*)w;                 // x_bf16 (33.5MB) then h bf16 (67MB)
    unsigned short* hw = (unsigned short*)(w + 67108864);    // 67 MB
    float* partials    = (float*)(w + 134217728);            // 16.8 MB
    char* meta = w + 150994944;
    int*   offs   = (int*)meta;            meta += 4352;
    int*   ecol   = (int*)meta;            meta += ECAP * 4;
    float* ewt    = (float*)meta;          meta += ECAP * 4;
    float* stats1 = (float*)meta;          meta += 512 * 4;   // stats1+stats2 contiguous (zeroed by build)
    float* stats2 = (float*)meta;          meta += 512 * 4;
    float* scale1 = (float*)meta;          meta += 256 * 4;
    float* shift1 = (float*)meta;          meta += 256 * 4;
    float* scale2 = (float*)meta;          meta += 256 * 4;
    float* shift2 = (float*)meta;          meta += 256 * 4;
    unsigned short* wt1 = (unsigned short*)meta;  meta += 256 * 128 * 2;
    unsigned short* wt2 = (unsigned short*)meta;  meta += 256 * 256 * 2;
    unsigned short* wt3 = (unsigned short*)meta;  meta += 256 * 256 * 2;

    const dim3 ggrid(2, NTOTAL / 128);   // (n-tiles, m-tiles) = (2, 1024)
    const int  P = NTOTAL / NB;          // 8192

    build_kernel<<<1, 1024, 0, stream>>>(ei, E, offs, ecol, ewt, stats1);
    xcvt_kernel<<<1024, 256, 0, stream>>>(x, hA, NTOTAL * FEAT_IN);
    wt_kernel<<<FEAT_IN, 256, 0, stream>>>(W1, wt1, FEAT_IN);
    wt_kernel<<<DHID, 256, 0, stream>>>(W2, wt2, DHID);
    wt_kernel<<<DHID, 256, 0, stream>>>(W3, wt3, DHID);

    // Layer 1
    mgemm_kernel<false><<<ggrid, 256, 0, stream>>>(hA, wt1, hw, FEAT_IN, nullptr, nullptr);
    spmm_kernel<true, false><<<P, 256, 0, stream>>>(hw, b1, hA, partials, offs, ecol, ewt);
    reduce_kernel<<<64, 256, 0, stream>>>(partials, stats1, P);
    finalize_kernel<<<1, 256, 0, stream>>>(stats1, gamma1, beta1, scale1, shift1);

    // Layer 2
    mgemm_kernel<true><<<ggrid, 256, 0, stream>>>(hA, wt2, hw, DHID, scale1, shift1);
    spmm_kernel<true, false><<<P, 256, 0, stream>>>(hw, b2, hA, partials, offs, ecol, ewt);
    reduce_kernel<<<64, 256, 0, stream>>>(partials, stats2, P);
    finalize_kernel<<<1, 256, 0, stream>>>(stats2, gamma2, beta2, scale2, shift2);

    // Layer 3 (fp32 output, no stats)
    mgemm_kernel<true><<<ggrid, 256, 0, stream>>>(hA, wt3, hw, DHID, scale2, shift2);
    spmm_kernel<false, true><<<P, 256, 0, stream>>>(hw, b3, out, nullptr, offs, ecol, ewt);
}

// Round 6
// 376.080 us; speedup vs baseline: 3.6806x; 1.0165x over previous
//
#include <hip/hip_runtime.h>

// Problem constants (fixed instance):
//   B=128 graphs, N=1024 nodes/graph, F=128 in-feats, D=256 hidden, E=8192 edges/graph
#define NNODES   1024
#define NGRAPH   128
#define NTOTAL   (NNODES * NGRAPH)   // 131072
#define FEAT_IN  128
#define DHID     256
#define ECAP     (16384 + NNODES)    // CSR capacity

typedef __attribute__((ext_vector_type(8))) short bf16x8;
typedef __attribute__((ext_vector_type(4))) float f32x4;
typedef __attribute__((ext_vector_type(4))) unsigned short us4;

__device__ __forceinline__ unsigned short f2bf(float f) {
    unsigned int u = __float_as_uint(f);
    u += 0x7fffu + ((u >> 16) & 1u);           // RNE
    return (unsigned short)(u >> 16);
}
__device__ __forceinline__ float bf2f(unsigned short s) {
    return __uint_as_float(((unsigned int)s) << 16);
}
__device__ __forceinline__ float blo(unsigned int u) { return __uint_as_float(u << 16); }
__device__ __forceinline__ float bhi(unsigned int u) { return __uint_as_float(u & 0xffff0000u); }

// ---------------- build: degree, dinv, CSR (by dst, incl self-loops), rowsum, zero stats --------
__global__ __launch_bounds__(1024) void build_kernel(
    const int* __restrict__ ei, int E,
    int* __restrict__ offs, int* __restrict__ ecol, float* __restrict__ ew,
    float* __restrict__ rowsum,
    float* __restrict__ stats /* 1024 floats zeroed */)
{
    __shared__ int scnt[NNODES];
    __shared__ int bufA[NNODES];
    __shared__ int bufB[NNODES];
    __shared__ float sdinv[NNODES];
    const int t = threadIdx.x;

    scnt[t] = 1;              // self-loop
    stats[t] = 0.0f;
    __syncthreads();

    for (int e = t; e < E; e += 1024)
        atomicAdd(&scnt[ei[E + e]], 1);   // dst = ei[1][e]
    __syncthreads();

    const int deg = scnt[t];
    const float di = rsqrtf((float)deg);
    sdinv[t] = di;
    bufA[t] = deg;
    __syncthreads();

    // Hillis-Steele inclusive scan; 10 iterations (even) -> result lands in bufA, bufB free after.
    int* src = bufA; int* dst = bufB;
    for (int d = 1; d < NNODES; d <<= 1) {
        dst[t] = src[t] + (t >= d ? src[t - d] : 0);
        __syncthreads();
        int* tmp = src; src = dst; dst = tmp;
    }
    const int excl = src[t] - deg;
    offs[t] = excl;
    if (t == NNODES - 1) offs[NNODES] = src[t];

    ecol[excl] = t;
    ew[excl] = di * di;
    scnt[t] = excl + 1;

    float* fb = (float*)bufB;            // rowsum accumulator (bufB is free post-scan)
    fb[t] = di * di;                     // self-loop weight
    __syncthreads();

    for (int e = t; e < E; e += 1024) {
        const int s = ei[e];
        const int d = ei[E + e];
        const int pos = atomicAdd(&scnt[d], 1);
        const float wv = sdinv[s] * sdinv[d];
        ecol[pos] = s;
        ew[pos] = wv;
        atomicAdd(&fb[d], wv);
    }
    __syncthreads();
    rowsum[t] = fb[t];
}

// ---------------- prep: x fp32 -> bf16 -----------------------------------------------------------
__global__ __launch_bounds__(256) void xcvt_kernel(const float* __restrict__ x,
                                                   unsigned short* __restrict__ xb, int n)
{
    for (int i = (blockIdx.x * 256 + threadIdx.x) * 4; i < n; i += gridDim.x * 256 * 4) {
        const float4 v = *(const float4*)(x + i);
        ushort4 o;
        o.x = f2bf(v.x); o.y = f2bf(v.y); o.z = f2bf(v.z); o.w = f2bf(v.w);
        *(ushort4*)(xb + i) = o;
    }
}

// ---------------- W prep: Wt[n][k] = bf16(scale[k]*W[k][n]) ; cvec[n] = sum_k shift[k]*W[k][n] ---
__global__ __launch_bounds__(256) void wprep_kernel(
    const float* __restrict__ W, const float* __restrict__ scale,
    const float* __restrict__ shift, unsigned short* __restrict__ Wt,
    float* __restrict__ cvec, int K)
{
    __shared__ float red[256];
    const int n = blockIdx.x, k = threadIdx.x;
    float sh = 0.0f;
    if (k < K) {
        const float wv = W[(size_t)k * DHID + n];
        const float sc = scale ? scale[k] : 1.0f;
        if (shift) sh = shift[k] * wv;
        Wt[(size_t)n * K + k] = f2bf(sc * wv);
    }
    red[k] = sh;
    __syncthreads();
    for (int s = 128; s > 0; s >>= 1) {
        if (k < s) red[k] += red[k + s];
        __syncthreads();
    }
    if (k == 0) cvec[n] = red[0];
}

// ---------------- MFMA GEMM: C[M][256] = bf16(A @ Wt^T) ------------------------------------------
// Pure bf16 GEMM. 128x128 tile, BK=64, 4 waves (2x2), 4x4 frags of 16x16x32.
// Staging via global_load_lds width-16, double-buffered, prefetch-before-compute.
// LDS layout [row][64k] linear; XOR swizzle (byte ^= (row&7)<<4) realized by
// pre-swizzling the GLOBAL source segment (linear LDS dest) + swizzled ds_read.
#define GBK 64

__global__ __launch_bounds__(256) void mgemm_kernel(
    const unsigned short* __restrict__ A,
    const unsigned short* __restrict__ Wt,
    unsigned short* __restrict__ C, int K)
{
    __shared__ unsigned short sA[2][128 * GBK];
    __shared__ unsigned short sB[2][128 * GBK];

    const int t = threadIdx.x;
    const int m0 = blockIdx.y * 128;
    const int n0 = blockIdx.x * 128;
    const int w = t >> 6, lane = t & 63;
    const int wr = w >> 1, wc = w & 1;
    const int lr = lane & 15, lk = lane >> 4;

    const int srow = lane >> 3;               // 0..7 within the 8-row group
    const int seg_src = (lane & 7) ^ srow;    // inverse-swizzled source segment

    f32x4 acc[4][4];
    #pragma unroll
    for (int i = 0; i < 4; ++i)
        #pragma unroll
        for (int j = 0; j < 4; ++j)
            acc[i][j] = (f32x4){0.f, 0.f, 0.f, 0.f};

    const int nsteps = K >> 6;

    auto stage = [&](int buf, int k0) {
        #pragma unroll
        for (int i = 0; i < 4; ++i) {
            const int row = (w * 4 + i) * 8 + srow;
            const unsigned short* ga = A + (size_t)(m0 + row) * K + k0 + seg_src * 8;
            __builtin_amdgcn_global_load_lds(
                (const __attribute__((address_space(1))) unsigned int*)ga,
                (__attribute__((address_space(3))) unsigned int*)&sA[buf][(w * 4 + i) * 512],
                16, 0, 0);
            const unsigned short* gb = Wt + (size_t)(n0 + row) * K + k0 + seg_src * 8;
            __builtin_amdgcn_global_load_lds(
                (const __attribute__((address_space(1))) unsigned int*)gb,
                (__attribute__((address_space(3))) unsigned int*)&sB[buf][(w * 4 + i) * 512],
                16, 0, 0);
        }
    };

    stage(0, 0);
    __syncthreads();   // compiler drains vmcnt before s_barrier

    for (int s = 0; s < nsteps; ++s) {
        if (s + 1 < nsteps) stage((s + 1) & 1, (s + 1) * GBK);
        const char* pa = (const char*)sA[s & 1];
        const char* pb = (const char*)sB[s & 1];
        #pragma unroll
        for (int ks = 0; ks < 2; ++ks) {
            bf16x8 af[4], bfv[4];
            #pragma unroll
            for (int f = 0; f < 4; ++f) {
                const int ra = wr * 64 + f * 16 + lr;
                af[f] = *(const bf16x8*)(pa + ra * 128 + ((ks * 64 + lk * 16) ^ ((ra & 7) << 4)));
                const int rb = wc * 64 + f * 16 + lr;
                bfv[f] = *(const bf16x8*)(pb + rb * 128 + ((ks * 64 + lk * 16) ^ ((rb & 7) << 4)));
            }
            #pragma unroll
            for (int mf = 0; mf < 4; ++mf)
                #pragma unroll
                for (int nf = 0; nf < 4; ++nf)
                    acc[mf][nf] = __builtin_amdgcn_mfma_f32_16x16x32_bf16(
                        af[mf], bfv[nf], acc[mf][nf], 0, 0, 0);
        }
        __syncthreads();
    }

    // C/D layout: col = lane&15, row = (lane>>4)*4 + reg
    #pragma unroll
    for (int mf = 0; mf < 4; ++mf) {
        const int rbase = m0 + wr * 64 + mf * 16 + lk * 4;
        #pragma unroll
        for (int nf = 0; nf < 4; ++nf) {
            const int c = n0 + wc * 64 + nf * 16 + lr;
            #pragma unroll
            for (int r = 0; r < 4; ++r)
                C[(size_t)(rbase + r) * DHID + c] = f2bf(acc[mf][nf][r]);
        }
    }
}

// ---------------- SpMM: h = relu(Anorm @ hw + rowsum*c + b), vectorized 4-feat/lane --------------
#define NB 16
#define ECAPB 512

template<bool STATS, bool OUTF32>
__global__ __launch_bounds__(256) void spmm_kernel(
    const unsigned short* __restrict__ hw, const float* __restrict__ bias,
    const float* __restrict__ rowsum, const float* __restrict__ cvec,
    void* __restrict__ hout, float* __restrict__ partials,
    const int* __restrict__ offs, const int* __restrict__ ecol,
    const float* __restrict__ ew)
{
    __shared__ int se[ECAPB];
    __shared__ float swt[ECAPB];
    __shared__ int soff[NB + 1];
    __shared__ float spartS[4][256];
    __shared__ float spartQ[4][256];

    const int b = blockIdx.x;                 // 8192 blocks
    const int xcd = b & 7;
    const int idx = b >> 3;
    const int g  = (idx >> 6) * 8 + xcd;      // all 64 blocks of graph g on one XCD
    const int nb = (idx & 63) * NB;
    const int t = threadIdx.x;
    const int w = t >> 6, l = t & 63;
    const int f0 = l * 4;
    const unsigned short* __restrict__ hwg = hw + (size_t)g * NNODES * DHID;

    if (t <= NB) soff[t] = offs[nb + t];
    __syncthreads();
    const int base = soff[0];
    const int tot = soff[NB] - base;          // ~150, cap 512
    for (int e = t; e < tot; e += 256) { se[e] = ecol[base + e]; swt[e] = ew[base + e]; }
    __syncthreads();

    const float4 bv = *(const float4*)(bias + f0);
    const float4 cv = *(const float4*)(cvec + f0);
    float ps0=0, ps1=0, ps2=0, ps3=0, pq0=0, pq1=0, pq2=0, pq3=0;

    #pragma unroll 1
    for (int j = 0; j < 4; ++j) {
        const int i = w * 4 + j;
        const int s = soff[i] - base, e = soff[i + 1] - base;
        const float rs = rowsum[nb + i];
        float a0=0, a1=0, a2=0, a3=0;
        int k = s;
        #pragma unroll 1
        for (; k + 4 <= e; k += 4) {
            const uint2 u0 = *(const uint2*)(hwg + (size_t)se[k+0] * DHID + f0);
            const uint2 u1 = *(const uint2*)(hwg + (size_t)se[k+1] * DHID + f0);
            const uint2 u2 = *(const uint2*)(hwg + (size_t)se[k+2] * DHID + f0);
            const uint2 u3 = *(const uint2*)(hwg + (size_t)se[k+3] * DHID + f0);
            const float w0 = swt[k+0], w1 = swt[k+1], w2 = swt[k+2], w3 = swt[k+3];
            a0 = fmaf(w0, blo(u0.x), a0); a1 = fmaf(w0, bhi(u0.x), a1);
            a2 = fmaf(w0, blo(u0.y), a2); a3 = fmaf(w0, bhi(u0.y), a3);
            a0 = fmaf(w1, blo(u1.x), a0); a1 = fmaf(w1, bhi(u1.x), a1);
            a2 = fmaf(w1, blo(u1.y), a2); a3 = fmaf(w1, bhi(u1.y), a3);
            a0 = fmaf(w2, blo(u2.x), a0); a1 = fmaf(w2, bhi(u2.x), a1);
            a2 = fmaf(w2, blo(u2.y), a2); a3 = fmaf(w2, bhi(u2.y), a3);
            a0 = fmaf(w3, blo(u3.x), a0); a1 = fmaf(w3, bhi(u3.x), a1);
            a2 = fmaf(w3, blo(u3.y), a2); a3 = fmaf(w3, bhi(u3.y), a3);
        }
        #pragma unroll 1
        for (; k < e; ++k) {
            const uint2 u = *(const uint2*)(hwg + (size_t)se[k] * DHID + f0);
            const float wk = swt[k];
            a0 = fmaf(wk, blo(u.x), a0); a1 = fmaf(wk, bhi(u.x), a1);
            a2 = fmaf(wk, blo(u.y), a2); a3 = fmaf(wk, bhi(u.y), a3);
        }

        const float v0 = fmaxf(fmaf(rs, cv.x, a0) + bv.x, 0.0f);
        const float v1 = fmaxf(fmaf(rs, cv.y, a1) + bv.y, 0.0f);
        const float v2 = fmaxf(fmaf(rs, cv.z, a2) + bv.z, 0.0f);
        const float v3 = fmaxf(fmaf(rs, cv.w, a3) + bv.w, 0.0f);
        const size_t orow = (size_t)g * NNODES + nb + i;
        if (OUTF32) {
            *(float4*)((float*)hout + orow * DHID + f0) = make_float4(v0, v1, v2, v3);
        } else {
            us4 o; o[0] = f2bf(v0); o[1] = f2bf(v1); o[2] = f2bf(v2); o[3] = f2bf(v3);
            *(us4*)((unsigned short*)hout + orow * DHID + f0) = o;
        }
        if (STATS) {
            ps0 += v0; ps1 += v1; ps2 += v2; ps3 += v3;
            pq0 += v0*v0; pq1 += v1*v1; pq2 += v2*v2; pq3 += v3*v3;
        }
    }

    if (STATS) {
        spartS[w][f0+0] = ps0; spartS[w][f0+1] = ps1; spartS[w][f0+2] = ps2; spartS[w][f0+3] = ps3;
        spartQ[w][f0+0] = pq0; spartQ[w][f0+1] = pq1; spartQ[w][f0+2] = pq2; spartQ[w][f0+3] = pq3;
        __syncthreads();
        const float ss = spartS[0][t] + spartS[1][t] + spartS[2][t] + spartS[3][t];
        const float sq = spartQ[0][t] + spartQ[1][t] + spartQ[2][t] + spartQ[3][t];
        partials[(size_t)b * 512 + t] = ss;
        partials[(size_t)b * 512 + 256 + t] = sq;
    }
}

// ---------------- stats reduce + BN scale/shift finalize -----------------------------------------
__global__ __launch_bounds__(256) void reduce_kernel(
    const float* __restrict__ partials, float* __restrict__ stats, int P)
{
    const int t = threadIdx.x;
    const int per = P / gridDim.x;
    const int p0 = blockIdx.x * per;
    float s = 0.0f, q = 0.0f;
    for (int p = p0; p < p0 + per; ++p) {
        s += partials[(size_t)p * 512 + t];
        q += partials[(size_t)p * 512 + 256 + t];
    }
    atomicAdd(&stats[t], s);
    atomicAdd(&stats[256 + t], q);
}

__global__ __launch_bounds__(256) void finalize_kernel(
    const float* __restrict__ stats, const float* __restrict__ gamma,
    const float* __restrict__ beta, float* __restrict__ scale,
    float* __restrict__ shift)
{
    const int t = threadIdx.x;
    const float n = (float)NTOTAL;
    const float mean = stats[t] / n;
    const float var = stats[256 + t] / n - mean * mean;
    const float sc = gamma[t] * rsqrtf(var + 1e-5f);
    scale[t] = sc;
    shift[t] = beta[t] - mean * sc;
}

// ---------------- launch -------------------------------------------------------------------------
extern "C" void kernel_launch(void* const* d_in, const int* in_sizes, int n_in,
                              void* d_out, int out_size, void* d_ws, size_t ws_size,
                              hipStream_t stream)
{
    const float* x      = (const float*)d_in[0];
    const int*   ei     = (const int*)d_in[1];
    const float* W1     = (const float*)d_in[3];
    const float* b1     = (const float*)d_in[4];
    const float* W2     = (const float*)d_in[5];
    const float* b2     = (const float*)d_in[6];
    const float* W3     = (const float*)d_in[7];
    const float* b3     = (const float*)d_in[8];
    const float* gamma1 = (const float*)d_in[9];
    const float* beta1  = (const float*)d_in[10];
    const float* gamma2 = (const float*)d_in[11];
    const float* beta2  = (const float*)d_in[12];
    float* out = (float*)d_out;

    const int E = in_sizes[1] / 2;   // 8192

    // workspace layout (total ~152 MB)
    char* w = (char*)d_ws;
    unsigned short* hA = (unsigned short*)w;                 // x_bf16 (33.5MB) then h bf16 (67MB)
    unsigned short* hw = (unsigned short*)(w + 67108864);    // 67 MB
    float* partials    = (float*)(w + 134217728);            // 16.8 MB
    char* meta = w + 150994944;
    int*   offs   = (int*)meta;            meta += 4352;
    int*   ecol   = (int*)meta;            meta += ECAP * 4;
    float* ewt    = (float*)meta;          meta += ECAP * 4;
    float* stats1 = (float*)meta;          meta += 512 * 4;   // stats1+stats2 contiguous (zeroed by build)
    float* stats2 = (float*)meta;          meta += 512 * 4;
    float* scale1 = (float*)meta;          meta += 256 * 4;
    float* shift1 = (float*)meta;          meta += 256 * 4;
    float* scale2 = (float*)meta;          meta += 256 * 4;
    float* shift2 = (float*)meta;          meta += 256 * 4;
    float* rowsum = (float*)meta;          meta += NNODES * 4;
    float* cvec1  = (float*)meta;          meta += 256 * 4;
    float* cvec2  = (float*)meta;          meta += 256 * 4;
    float* cvec3  = (float*)meta;          meta += 256 * 4;
    unsigned short* wt1 = (unsigned short*)meta;  meta += 256 * 128 * 2;
    unsigned short* wt2 = (unsigned short*)meta;  meta += 256 * 256 * 2;
    unsigned short* wt3 = (unsigned short*)meta;  meta += 256 * 256 * 2;

    const dim3 ggrid(2, NTOTAL / 128);   // (n-tiles, m-tiles) = (2, 1024)
    const int  P = NTOTAL / NB;          // 8192

    build_kernel<<<1, 1024, 0, stream>>>(ei, E, offs, ecol, ewt, rowsum, stats1);
    xcvt_kernel<<<1024, 256, 0, stream>>>(x, hA, NTOTAL * FEAT_IN);
    wprep_kernel<<<DHID, 256, 0, stream>>>(W1, nullptr, nullptr, wt1, cvec1, FEAT_IN);

    // Layer 1
    mgemm_kernel<<<ggrid, 256, 0, stream>>>(hA, wt1, hw, FEAT_IN);
    spmm_kernel<true, false><<<P, 256, 0, stream>>>(hw, b1, rowsum, cvec1, hA, partials, offs, ecol, ewt);
    reduce_kernel<<<64, 256, 0, stream>>>(partials, stats1, P);
    finalize_kernel<<<1, 256, 0, stream>>>(stats1, gamma1, beta1, scale1, shift1);
    wprep_kernel<<<DHID, 256, 0, stream>>>(W2, scale1, shift1, wt2, cvec2, DHID);

    // Layer 2
    mgemm_kernel<<<ggrid, 256, 0, stream>>>(hA, wt2, hw, DHID);
    spmm_kernel<true, false><<<P, 256, 0, stream>>>(hw, b2, rowsum, cvec2, hA, partials, offs, ecol, ewt);
    reduce_kernel<<<64, 256, 0, stream>>>(partials, stats2, P);
    finalize_kernel<<<1, 256, 0, stream>>>(stats2, gamma2, beta2, scale2, shift2);
    wprep_kernel<<<DHID, 256, 0, stream>>>(W3, scale2, shift2, wt3, cvec3, DHID);

    // Layer 3 (fp32 output, no stats)
    mgemm_kernel<<<ggrid, 256, 0, stream>>>(hA, wt3, hw, DHID);
    spmm_kernel<false, true><<<P, 256, 0, stream>>>(hw, b3, rowsum, cvec3, out, nullptr, offs, ecol, ewt);
}

// Round 7
// 357.934 us; speedup vs baseline: 3.8672x; 1.0507x over previous
//
#include <hip/hip_runtime.h>

// Problem constants (fixed instance):
//   B=128 graphs, N=1024 nodes/graph, F=128 in-feats, D=256 hidden, E=8192 edges/graph
#define NNODES   1024
#define NGRAPH   128
#define NTOTAL   (NNODES * NGRAPH)   // 131072
#define FEAT_IN  128
#define DHID     256
#define ECAP     (16384 + NNODES)    // CSR capacity

typedef __attribute__((ext_vector_type(8))) short bf16x8;
typedef __attribute__((ext_vector_type(4))) float f32x4;
typedef __attribute__((ext_vector_type(4))) unsigned short us4;
typedef __attribute__((ext_vector_type(8))) unsigned short us8;

__device__ __forceinline__ unsigned short f2bf(float f) {
    unsigned int u = __float_as_uint(f);
    u += 0x7fffu + ((u >> 16) & 1u);           // RNE
    return (unsigned short)(u >> 16);
}
__device__ __forceinline__ float bf2f(unsigned short s) {
    return __uint_as_float(((unsigned int)s) << 16);
}
__device__ __forceinline__ float blo(unsigned int u) { return __uint_as_float(u << 16); }
__device__ __forceinline__ float bhi(unsigned int u) { return __uint_as_float(u & 0xffff0000u); }

// ---------------- build: degree, dinv, CSR (by dst, incl self-loops), rowsum, zero stats --------
__global__ __launch_bounds__(1024) void build_kernel(
    const int* __restrict__ ei, int E,
    int* __restrict__ offs, int* __restrict__ ecol, float* __restrict__ ew,
    float* __restrict__ rowsum,
    float* __restrict__ stats /* 1024 floats zeroed */)
{
    __shared__ int scnt[NNODES];
    __shared__ int bufA[NNODES];
    __shared__ int bufB[NNODES];
    __shared__ float sdinv[NNODES];
    const int t = threadIdx.x;

    scnt[t] = 1;              // self-loop
    stats[t] = 0.0f;
    __syncthreads();

    for (int e = t; e < E; e += 1024)
        atomicAdd(&scnt[ei[E + e]], 1);   // dst = ei[1][e]
    __syncthreads();

    const int deg = scnt[t];
    const float di = rsqrtf((float)deg);
    sdinv[t] = di;
    bufA[t] = deg;
    __syncthreads();

    int* src = bufA; int* dst = bufB;
    for (int d = 1; d < NNODES; d <<= 1) {
        dst[t] = src[t] + (t >= d ? src[t - d] : 0);
        __syncthreads();
        int* tmp = src; src = dst; dst = tmp;
    }
    const int excl = src[t] - deg;
    offs[t] = excl;
    if (t == NNODES - 1) offs[NNODES] = src[t];

    ecol[excl] = t;
    ew[excl] = di * di;
    scnt[t] = excl + 1;

    float* fb = (float*)bufB;            // rowsum accumulator (bufB free post-scan, 10 iters even)
    fb[t] = di * di;                     // self-loop weight
    __syncthreads();

    for (int e = t; e < E; e += 1024) {
        const int s = ei[e];
        const int d = ei[E + e];
        const int pos = atomicAdd(&scnt[d], 1);
        const float wv = sdinv[s] * sdinv[d];
        ecol[pos] = s;
        ew[pos] = wv;
        atomicAdd(&fb[d], wv);
    }
    __syncthreads();
    rowsum[t] = fb[t];
}

// ---------------- W1 prep (no BN): Wt[n][k] = bf16(W[k][n]) ; cvec[n] = 0 ------------------------
__global__ __launch_bounds__(256) void wprep_kernel(
    const float* __restrict__ W, unsigned short* __restrict__ Wt,
    float* __restrict__ cvec, int K)
{
    const int n = blockIdx.x, k = threadIdx.x;
    if (k < K) Wt[(size_t)n * K + k] = f2bf(W[(size_t)k * DHID + n]);
    if (k == 0) cvec[n] = 0.0f;
}

// ---------------- fused BN-finalize + W prep -----------------------------------------------------
// Each block replicates the (cheap) per-feature finalize from stats, then preps its column n:
//   Wt[n][k] = bf16(scale[k] * W[k][n]) ; cvec[n] = sum_k shift[k] * W[k][n]
__global__ __launch_bounds__(256) void bnwprep_kernel(
    const float* __restrict__ stats, const float* __restrict__ gamma,
    const float* __restrict__ beta, const float* __restrict__ W,
    unsigned short* __restrict__ Wt, float* __restrict__ cvec)
{
    __shared__ float red[256];
    const int n = blockIdx.x, k = threadIdx.x;
    const float nn = (float)NTOTAL;
    const float mean = stats[k] / nn;
    const float var = stats[256 + k] / nn - mean * mean;
    const float sc = gamma[k] * rsqrtf(var + 1e-5f);
    const float sh = beta[k] - mean * sc;
    const float wv = W[(size_t)k * DHID + n];
    Wt[(size_t)n * DHID + k] = f2bf(sc * wv);
    red[k] = sh * wv;
    __syncthreads();
    for (int s = 128; s > 0; s >>= 1) {
        if (k < s) red[k] += red[k + s];
        __syncthreads();
    }
    if (k == 0) cvec[n] = red[0];
}

// ---------------- MFMA GEMM: C[M][256] = bf16(A @ Wt^T) ------------------------------------------
// 128x128 tile, BK=64, 4 waves (2x2), 4x4 frags of 16x16x32.
// CVT=0: A bf16, staged via global_load_lds w16, double-buffered (linear dest,
//        inverse-swizzled global source segment, swizzled ds_read).
// CVT=1: A fp32 (the raw x input), reg-staged + RNE->bf16 + swizzled ds_write;
//        B still global_load_lds. Single-buffered (K=128 -> 2 steps).
// Block decode (1D grid 2048): the two n-tiles of an m-panel are consecutive
// blocks on the SAME XCD -> second A-panel read hits that XCD's L2.
#define GBK 64

template<bool CVT>
__global__ __launch_bounds__(256) void mgemm_kernel(
    const void* __restrict__ Ain,
    const unsigned short* __restrict__ Wt,
    unsigned short* __restrict__ C, int K)
{
    constexpr int NBUF = CVT ? 1 : 2;
    __shared__ unsigned short sA[NBUF][128 * GBK];
    __shared__ unsigned short sB[NBUF][128 * GBK];

    const int t = threadIdx.x;
    const int bid = blockIdx.x;
    const int xcd = bid & 7, kk_ = bid >> 3;
    const int m0 = ((kk_ >> 1) * 8 + xcd) * 128;
    const int n0 = (kk_ & 1) * 128;

    const int w = t >> 6, lane = t & 63;
    const int wr = w >> 1, wc = w & 1;
    const int lr = lane & 15, lk = lane >> 4;

    const int srow = lane >> 3;               // 0..7 within the 8-row group
    const int seg_src = (lane & 7) ^ srow;    // inverse-swizzled source segment

    f32x4 acc[4][4];
    #pragma unroll
    for (int i = 0; i < 4; ++i)
        #pragma unroll
        for (int j = 0; j < 4; ++j)
            acc[i][j] = (f32x4){0.f, 0.f, 0.f, 0.f};

    const int nsteps = K >> 6;

    auto stageB = [&](int buf, int k0) {
        #pragma unroll
        for (int i = 0; i < 4; ++i) {
            const int row = (w * 4 + i) * 8 + srow;
            const unsigned short* gb = Wt + (size_t)(n0 + row) * K + k0 + seg_src * 8;
            __builtin_amdgcn_global_load_lds(
                (const __attribute__((address_space(1))) unsigned int*)gb,
                (__attribute__((address_space(3))) unsigned int*)&sB[buf][(w * 4 + i) * 512],
                16, 0, 0);
        }
    };
    auto stageA_lds = [&](int buf, int k0) {
        #pragma unroll
        for (int i = 0; i < 4; ++i) {
            const int row = (w * 4 + i) * 8 + srow;
            const unsigned short* ga = (const unsigned short*)Ain + (size_t)(m0 + row) * K + k0 + seg_src * 8;
            __builtin_amdgcn_global_load_lds(
                (const __attribute__((address_space(1))) unsigned int*)ga,
                (__attribute__((address_space(3))) unsigned int*)&sA[buf][(w * 4 + i) * 512],
                16, 0, 0);
        }
    };

    auto compute = [&](int buf) {
        const char* pa = (const char*)sA[buf];
        const char* pb = (const char*)sB[buf];
        #pragma unroll
        for (int ks = 0; ks < 2; ++ks) {
            bf16x8 af[4], bfv[4];
            #pragma unroll
            for (int f = 0; f < 4; ++f) {
                const int ra = wr * 64 + f * 16 + lr;
                af[f] = *(const bf16x8*)(pa + ra * 128 + ((ks * 64 + lk * 16) ^ ((ra & 7) << 4)));
                const int rb = wc * 64 + f * 16 + lr;
                bfv[f] = *(const bf16x8*)(pb + rb * 128 + ((ks * 64 + lk * 16) ^ ((rb & 7) << 4)));
            }
            #pragma unroll
            for (int mf = 0; mf < 4; ++mf)
                #pragma unroll
                for (int nf = 0; nf < 4; ++nf)
                    acc[mf][nf] = __builtin_amdgcn_mfma_f32_16x16x32_bf16(
                        af[mf], bfv[nf], acc[mf][nf], 0, 0, 0);
        }
    };

    if constexpr (CVT) {
        const float* Af = (const float*)Ain;
        const int r = t >> 1, kh = (t & 1) * 32;   // this thread: row r, k-range [kh, kh+32)
        for (int s = 0; s < nsteps; ++s) {
            if (s > 0) __syncthreads();            // protect buffers from previous compute
            stageB(0, s * GBK);
            // A: load 32 fp32, convert, swizzle-write 4x 16B slots
            const float* ga = Af + (size_t)(m0 + r) * K + s * GBK + kh;
            #pragma unroll
            for (int j = 0; j < 4; ++j) {
                const float4 v0 = *(const float4*)(ga + j * 8);
                const float4 v1 = *(const float4*)(ga + j * 8 + 4);
                us8 o;
                o[0] = f2bf(v0.x); o[1] = f2bf(v0.y); o[2] = f2bf(v0.z); o[3] = f2bf(v0.w);
                o[4] = f2bf(v1.x); o[5] = f2bf(v1.y); o[6] = f2bf(v1.z); o[7] = f2bf(v1.w);
                const int slot = ((kh >> 3) + j) ^ (r & 7);
                *(us8*)&sA[0][r * 64 + slot * 8] = o;
            }
            __syncthreads();                       // drains B vmcnt + A lds writes
            compute(0);
        }
    } else {
        stageA_lds(0, 0);
        stageB(0, 0);
        __syncthreads();
        for (int s = 0; s < nsteps; ++s) {
            if (s + 1 < nsteps) { stageA_lds((s + 1) & 1, (s + 1) * GBK); stageB((s + 1) & 1, (s + 1) * GBK); }
            compute(s & 1);
            __syncthreads();
        }
    }

    // C/D layout: col = lane&15, row = (lane>>4)*4 + reg
    #pragma unroll
    for (int mf = 0; mf < 4; ++mf) {
        const int rbase = m0 + wr * 64 + mf * 16 + lk * 4;
        #pragma unroll
        for (int nf = 0; nf < 4; ++nf) {
            const int c = n0 + wc * 64 + nf * 16 + lr;
            #pragma unroll
            for (int r = 0; r < 4; ++r)
                C[(size_t)(rbase + r) * DHID + c] = f2bf(acc[mf][nf][r]);
        }
    }
}

// ---------------- SpMM: h = relu(Anorm @ hw + rowsum*c + b), vectorized 4-feat/lane --------------
#define NB 16
#define ECAPB 512

template<bool STATS, bool OUTF32>
__global__ __launch_bounds__(256) void spmm_kernel(
    const unsigned short* __restrict__ hw, const float* __restrict__ bias,
    const float* __restrict__ rowsum, const float* __restrict__ cvec,
    void* __restrict__ hout, float* __restrict__ partials,
    const int* __restrict__ offs, const int* __restrict__ ecol,
    const float* __restrict__ ew)
{
    __shared__ int se[ECAPB];
    __shared__ float swt[ECAPB];
    __shared__ int soff[NB + 1];
    __shared__ float spartS[4][256];
    __shared__ float spartQ[4][256];

    const int b = blockIdx.x;                 // 8192 blocks
    const int xcd = b & 7;
    const int idx = b >> 3;
    const int g  = (idx >> 6) * 8 + xcd;      // all 64 blocks of graph g on one XCD
    const int nb = (idx & 63) * NB;
    const int t = threadIdx.x;
    const int w = t >> 6, l = t & 63;
    const int f0 = l * 4;
    const unsigned short* __restrict__ hwg = hw + (size_t)g * NNODES * DHID;

    if (t <= NB) soff[t] = offs[nb + t];
    __syncthreads();
    const int base = soff[0];
    const int tot = soff[NB] - base;          // ~150, cap 512
    for (int e = t; e < tot; e += 256) { se[e] = ecol[base + e]; swt[e] = ew[base + e]; }
    __syncthreads();

    const float4 bv = *(const float4*)(bias + f0);
    const float4 cv = *(const float4*)(cvec + f0);
    float ps0=0, ps1=0, ps2=0, ps3=0, pq0=0, pq1=0, pq2=0, pq3=0;

    #pragma unroll 1
    for (int j = 0; j < 4; ++j) {
        const int i = w * 4 + j;
        const int s = soff[i] - base, e = soff[i + 1] - base;
        const float rs = rowsum[nb + i];
        float a0=0, a1=0, a2=0, a3=0;
        int k = s;
        #pragma unroll 1
        for (; k + 4 <= e; k += 4) {
            const uint2 u0 = *(const uint2*)(hwg + (size_t)se[k+0] * DHID + f0);
            const uint2 u1 = *(const uint2*)(hwg + (size_t)se[k+1] * DHID + f0);
            const uint2 u2 = *(const uint2*)(hwg + (size_t)se[k+2] * DHID + f0);
            const uint2 u3 = *(const uint2*)(hwg + (size_t)se[k+3] * DHID + f0);
            const float w0 = swt[k+0], w1 = swt[k+1], w2 = swt[k+2], w3 = swt[k+3];
            a0 = fmaf(w0, blo(u0.x), a0); a1 = fmaf(w0, bhi(u0.x), a1);
            a2 = fmaf(w0, blo(u0.y), a2); a3 = fmaf(w0, bhi(u0.y), a3);
            a0 = fmaf(w1, blo(u1.x), a0); a1 = fmaf(w1, bhi(u1.x), a1);
            a2 = fmaf(w1, blo(u1.y), a2); a3 = fmaf(w1, bhi(u1.y), a3);
            a0 = fmaf(w2, blo(u2.x), a0); a1 = fmaf(w2, bhi(u2.x), a1);
            a2 = fmaf(w2, blo(u2.y), a2); a3 = fmaf(w2, bhi(u2.y), a3);
            a0 = fmaf(w3, blo(u3.x), a0); a1 = fmaf(w3, bhi(u3.x), a1);
            a2 = fmaf(w3, blo(u3.y), a2); a3 = fmaf(w3, bhi(u3.y), a3);
        }
        #pragma unroll 1
        for (; k < e; ++k) {
            const uint2 u = *(const uint2*)(hwg + (size_t)se[k] * DHID + f0);
            const float wk = swt[k];
            a0 = fmaf(wk, blo(u.x), a0); a1 = fmaf(wk, bhi(u.x), a1);
            a2 = fmaf(wk, blo(u.y), a2); a3 = fmaf(wk, bhi(u.y), a3);
        }

        const float v0 = fmaxf(fmaf(rs, cv.x, a0) + bv.x, 0.0f);
        const float v1 = fmaxf(fmaf(rs, cv.y, a1) + bv.y, 0.0f);
        const float v2 = fmaxf(fmaf(rs, cv.z, a2) + bv.z, 0.0f);
        const float v3 = fmaxf(fmaf(rs, cv.w, a3) + bv.w, 0.0f);
        const size_t orow = (size_t)g * NNODES + nb + i;
        if (OUTF32) {
            *(float4*)((float*)hout + orow * DHID + f0) = make_float4(v0, v1, v2, v3);
        } else {
            us4 o; o[0] = f2bf(v0); o[1] = f2bf(v1); o[2] = f2bf(v2); o[3] = f2bf(v3);
            *(us4*)((unsigned short*)hout + orow * DHID + f0) = o;
        }
        if (STATS) {
            ps0 += v0; ps1 += v1; ps2 += v2; ps3 += v3;
            pq0 += v0*v0; pq1 += v1*v1; pq2 += v2*v2; pq3 += v3*v3;
        }
    }

    if (STATS) {
        spartS[w][f0+0] = ps0; spartS[w][f0+1] = ps1; spartS[w][f0+2] = ps2; spartS[w][f0+3] = ps3;
        spartQ[w][f0+0] = pq0; spartQ[w][f0+1] = pq1; spartQ[w][f0+2] = pq2; spartQ[w][f0+3] = pq3;
        __syncthreads();
        const float ss = spartS[0][t] + spartS[1][t] + spartS[2][t] + spartS[3][t];
        const float sq = spartQ[0][t] + spartQ[1][t] + spartQ[2][t] + spartQ[3][t];
        partials[(size_t)b * 512 + t] = ss;
        partials[(size_t)b * 512 + 256 + t] = sq;
    }
}

// ---------------- stats reduce ------------------------------------------------------------------
__global__ __launch_bounds__(256) void reduce_kernel(
    const float* __restrict__ partials, float* __restrict__ stats, int P)
{
    const int t = threadIdx.x;
    const int per = P / gridDim.x;
    const int p0 = blockIdx.x * per;
    float s = 0.0f, q = 0.0f;
    for (int p = p0; p < p0 + per; ++p) {
        s += partials[(size_t)p * 512 + t];
        q += partials[(size_t)p * 512 + 256 + t];
    }
    atomicAdd(&stats[t], s);
    atomicAdd(&stats[256 + t], q);
}

// ---------------- launch -------------------------------------------------------------------------
extern "C" void kernel_launch(void* const* d_in, const int* in_sizes, int n_in,
                              void* d_out, int out_size, void* d_ws, size_t ws_size,
                              hipStream_t stream)
{
    const float* x      = (const float*)d_in[0];
    const int*   ei     = (const int*)d_in[1];
    const float* W1     = (const float*)d_in[3];
    const float* b1     = (const float*)d_in[4];
    const float* W2     = (const float*)d_in[5];
    const float* b2     = (const float*)d_in[6];
    const float* W3     = (const float*)d_in[7];
    const float* b3     = (const float*)d_in[8];
    const float* gamma1 = (const float*)d_in[9];
    const float* beta1  = (const float*)d_in[10];
    const float* gamma2 = (const float*)d_in[11];
    const float* beta2  = (const float*)d_in[12];
    float* out = (float*)d_out;

    const int E = in_sizes[1] / 2;   // 8192

    // workspace layout (total ~152 MB)
    char* w = (char*)d_ws;
    unsigned short* hA = (unsigned short*)w;                 // h bf16 (67 MB)
    unsigned short* hw = (unsigned short*)(w + 67108864);    // 67 MB
    float* partials    = (float*)(w + 134217728);            // 16.8 MB
    char* meta = w + 150994944;
    int*   offs   = (int*)meta;            meta += 4352;
    int*   ecol   = (int*)meta;            meta += ECAP * 4;
    float* ewt    = (float*)meta;          meta += ECAP * 4;
    float* stats1 = (float*)meta;          meta += 512 * 4;   // stats1+stats2 contiguous (zeroed by build)
    float* stats2 = (float*)meta;          meta += 512 * 4;
    float* rowsum = (float*)meta;          meta += NNODES * 4;
    float* cvec1  = (float*)meta;          meta += 256 * 4;
    float* cvec2  = (float*)meta;          meta += 256 * 4;
    float* cvec3  = (float*)meta;          meta += 256 * 4;
    unsigned short* wt1 = (unsigned short*)meta;  meta += 256 * 128 * 2;
    unsigned short* wt2 = (unsigned short*)meta;  meta += 256 * 256 * 2;
    unsigned short* wt3 = (unsigned short*)meta;  meta += 256 * 256 * 2;

    const int GG = 2048;                 // 1D GEMM grid (pairing swizzle decoded in-kernel)
    const int P  = NTOTAL / NB;          // 8192

    build_kernel<<<1, 1024, 0, stream>>>(ei, E, offs, ecol, ewt, rowsum, stats1);
    wprep_kernel<<<DHID, 256, 0, stream>>>(W1, wt1, cvec1, FEAT_IN);

    // Layer 1 (x fp32 converted in-GEMM)
    mgemm_kernel<true><<<GG, 256, 0, stream>>>(x, wt1, hw, FEAT_IN);
    spmm_kernel<true, false><<<P, 256, 0, stream>>>(hw, b1, rowsum, cvec1, hA, partials, offs, ecol, ewt);
    reduce_kernel<<<64, 256, 0, stream>>>(partials, stats1, P);
    bnwprep_kernel<<<DHID, 256, 0, stream>>>(stats1, gamma1, beta1, W2, wt2, cvec2);

    // Layer 2
    mgemm_kernel<false><<<GG, 256, 0, stream>>>(hA, wt2, hw, DHID);
    spmm_kernel<true, false><<<P, 256, 0, stream>>>(hw, b2, rowsum, cvec2, hA, partials, offs, ecol, ewt);
    reduce_kernel<<<64, 256, 0, stream>>>(partials, stats2, P);
    bnwprep_kernel<<<DHID, 256, 0, stream>>>(stats2, gamma2, beta2, W3, wt3, cvec3);

    // Layer 3 (fp32 output, no stats)
    mgemm_kernel<false><<<GG, 256, 0, stream>>>(hA, wt3, hw, DHID);
    spmm_kernel<false, true><<<P, 256, 0, stream>>>(hw, b3, rowsum, cvec3, out, nullptr, offs, ecol, ewt);
}